// Round 1
// 301.411 us; speedup vs baseline: 1.0340x; 1.0340x over previous
//
#include <hip/hip_runtime.h>
#include <math.h>

#define FLAT   8192
#define NB     64
#define OD_    80
#define NE_    512
#define EATT_  4096
#define MAXACT 4096
// acc_glob: 96 floats/node, atomically accumulated by k_rgemm:
//   [0..31]  out_s partial (pre gate/env/norm)
//   [32..47] q (scalar coeff that multiplies yv)
//   [48..95] D-term out_v, layout comp*16 + o
#define ACCW 96

typedef __bf16 v8bf __attribute__((ext_vector_type(8)));
typedef float  v4f  __attribute__((ext_vector_type(4)));

__device__ __forceinline__ float silu_f(float x) { return x / (1.f + __expf(-x)); }
__device__ __forceinline__ float sigm_f(float x) { return 1.f / (1.f + __expf(-x)); }

// ---------------- init: zero acc + vabs, widx=-1, count=0 ----------------
__global__ void k_init(float* acc, float* vabs, int* widx, int* count) {
  int t = blockIdx.x * 256 + threadIdx.x;
  if (t < MAXACT * ACCW) acc[t] = 0.f;
  if (t < FLAT) widx[t] = -1;
  if (t < NB * OD_) vabs[t] = 0.f;
  if (t == 0) *count = 0;
}

// ---------------- scatter: last-write-wins == max edge index ----------------
__global__ void k_scatter(const int* __restrict__ att_dst, int* widx) {
  int i = blockIdx.x * 256 + threadIdx.x;
  if (i < EATT_) atomicMax(&widx[att_dst[i]], i);
}

// ---------------- compact active-node list ----------------
__global__ void k_build(const int* __restrict__ widx, int* active, int* count) {
  int j = blockIdx.x * 256 + threadIdx.x;
  if (j < FLAT && widx[j] >= 0) {
    int p = atomicAdd(count, 1);
    active[p] = j;
  }
}

// ---------------- per-batch absorber row of gate layer 1: h_abs @ wg1 ----------------
__global__ void k_gabs(const int* __restrict__ abs_idx, const float* __restrict__ h,
                       const float* __restrict__ wg1, float* habs_g) {
  int b = blockIdx.x;   // 64
  int t = threadIdx.x;  // 128
  __shared__ float hs[128];
  int nabs = abs_idx[b];
  hs[t] = h[(size_t)(b * 128 + nabs) * 128 + t];
  __syncthreads();
  float g = 0.f;
  for (int c = 0; c < 128; ++c) g = fmaf(hs[c], wg1[c * 128 + t], g);
  habs_g[b * 128 + t] = g;
}

// ---------------- transpose+split head weights to bf16 hi/lo, [n][k] ----------------
// wo2: [128k][128n] -> w2t_{h,l}[128n][128k]; wo3: [128k][256n] -> w3t[256n][128k]
__global__ void k_wprep(const float* __restrict__ wo2, const float* __restrict__ wo3,
                        __bf16* w2h, __bf16* w2l, __bf16* w3h, __bf16* w3l) {
  int b = blockIdx.x;   // 0..383
  int t = threadIdx.x;  // 128 = k index
  if (b < 128) {
    float v = wo2[t * 128 + b];
    __bf16 h = (__bf16)v;
    w2h[b * 128 + t] = h;
    w2l[b * 128 + t] = (__bf16)(v - (float)h);
  } else {
    int n = b - 128;
    float v = wo3[t * 256 + n];
    __bf16 h = (__bf16)v;
    w3h[n * 128 + t] = h;
    w3l[n * 128 + t] = (__bf16)(v - (float)h);
  }
}

// ---------------- per active node: rbf, hidden a(128), gate, env, coefs ----------------
__global__ void k_node(const int* __restrict__ count, const int* __restrict__ active,
                       const int* __restrict__ widx,
                       const float* __restrict__ att_dist, const float* __restrict__ att_vec,
                       const int* __restrict__ z, const float* __restrict__ w_zemb,
                       const int* __restrict__ abs_idx,
                       const float* __restrict__ w1_rad, const float* __restrict__ b1_rad,
                       const float* __restrict__ h, const float* __restrict__ habs_g,
                       const float* __restrict__ wg1, const float* __restrict__ bg1,
                       const float* __restrict__ wg2, const float* __restrict__ bg2,
                       const float* __restrict__ h_full,
                       float* a_glob, float* coef_glob, float* meta_f, int* meta_b) {
  int pos = blockIdx.x;
  if (pos >= *count) return;
  int t = threadIdx.x;  // 128 threads
  __shared__ float win[49];
  __shared__ float yv_s[3];
  __shared__ float red[128];
  __shared__ float sh_d;

  int j = active[pos];
  int b = j >> 7;
  int n = j & 127;
  int e = widx[j];

  if (t == 0) {
    float d = att_dist[e];
    sh_d = d;
    float eps = fmaxf(d, 1e-8f);
    const float s3 = 1.7320508075688772f;
    yv_s[0] = s3 * att_vec[e * 3 + 0] / eps;
    yv_s[1] = s3 * att_vec[e * 3 + 1] / eps;
    yv_s[2] = s3 * att_vec[e * 3 + 2] / eps;
  }
  int nabs = abs_idx[b];
  float isab = (n == nabs) ? 1.f : 0.f;
  if (t < 32) win[t] = w_zemb[z[j] * 32 + t];
  if (t == 32) win[32] = isab;
  if (t >= 33 && t < 49) {
    int k = t - 33;
    float d = att_dist[e];
    float x = (d - (float)k * (1.f / 3.f)) * 3.f;  // width = CUTOFF/(RBF-1) = 1/3
    win[t] = __expf(-0.5f * x * x);
  }
  __syncthreads();

  // hidden a = silu(win @ w1_rad + b1_rad)   (49 -> 128)
  {
    float s = b1_rad[t];
    for (int k = 0; k < 49; ++k) s = fmaf(win[k], w1_rad[k * 128 + t], s);
    a_glob[pos * 128 + t] = silu_f(s);
  }

  // gate MLP hidden (273 -> 128); h_abs part precomputed per-batch (k_gabs)
  {
    float g = bg1[t] + habs_g[b * 128 + t];
    const float* hn = h + (size_t)j * 128;
    for (int c = 0; c < 128; ++c) g = fmaf(hn[c], wg1[(128 + c) * 128 + t], g);
    for (int k = 0; k < 16; ++k)  g = fmaf(win[33 + k], wg1[(256 + k) * 128 + t], g);
    g = fmaf(isab, wg1[272 * 128 + t], g);
    red[t] = silu_f(g) * wg2[t];
  }
  __syncthreads();

  // per-node contraction coefficients: [s1(64), p*inv_s3(32), v1(96)]
  const float* hf = h_full + (size_t)j * 160;
  if (t < 64) coef_glob[pos * 192 + t] = hf[t];
  if (t >= 64 && t < 96) {
    int i = t - 64;
    float pv = hf[64 + i * 3 + 0] * yv_s[0] + hf[64 + i * 3 + 1] * yv_s[1] +
               hf[64 + i * 3 + 2] * yv_s[2];
    coef_glob[pos * 192 + t] = pv * 0.5773502691896258f;
  }
  if (t < 96) coef_glob[pos * 192 + 96 + t] = hf[64 + t];

  if (t == 0) {
    float tot = 0.f;
    for (int k = 0; k < 128; ++k) tot += red[k];
    tot += bg2[0];
    float gate = sigm_f(tot);
    float d = sh_d;
    float env = (d < 5.f) ? 0.5f * (__cosf(3.14159265358979323846f * d * 0.2f) + 1.f) : 0.f;
    meta_f[pos * 4 + 0] = yv_s[0];
    meta_f[pos * 4 + 1] = yv_s[1];
    meta_f[pos * 4 + 2] = yv_s[2];
    meta_f[pos * 4 + 3] = gate * env;
    meta_b[pos] = b;
  }
}

// ---------------- radial GEMM + fused contraction (R7-proven, unchanged) ----------------
__global__ __launch_bounds__(256) void k_rgemm(const int* __restrict__ count,
                                               const float* __restrict__ a_glob,
                                               const float* __restrict__ coef_glob,
                                               const float* __restrict__ w2,
                                               const float* __restrict__ b2,
                                               float* __restrict__ acc_glob) {
  int cc = blockIdx.x;         // 0..35 (col chunk of 128)
  int nbase = blockIdx.y * 64;
  if (nbase >= *count) return;
  int t = threadIdx.x;
  int tx = t & 15, ty = t >> 4;
  int n0 = ty * 4;

  __shared__ float w_s[2][16][128];  // 16 KB
  __shared__ float a_s[2][16][64];   // 8 KB (transposed [k][node])

  const float* wbase = w2 + cc * 128;
  int wr = t >> 5;             // 0..7; rows wr and wr+8
  int wc4 = t & 31;            // col/4
  int anode = t >> 2, aq = t & 3;
  const float* aptr = a_glob + (size_t)(nbase + anode) * 128 + aq * 4;

  float4 wpre0, wpre1, apre;
  wpre0 = *(const float4*)(wbase + (size_t)wr * 4608 + wc4 * 4);
  wpre1 = *(const float4*)(wbase + (size_t)(wr + 8) * 4608 + wc4 * 4);
  apre  = *(const float4*)aptr;
  *(float4*)&w_s[0][wr][wc4 * 4]     = wpre0;
  *(float4*)&w_s[0][wr + 8][wc4 * 4] = wpre1;
  a_s[0][aq * 4 + 0][anode] = apre.x;
  a_s[0][aq * 4 + 1][anode] = apre.y;
  a_s[0][aq * 4 + 2][anode] = apre.z;
  a_s[0][aq * 4 + 3][anode] = apre.w;
  __syncthreads();

  float acc[4][8];
#pragma unroll
  for (int i = 0; i < 4; ++i)
#pragma unroll
    for (int j = 0; j < 8; ++j) acc[i][j] = 0.f;

  for (int kb = 0; kb < 8; ++kb) {
    int cur = kb & 1;
    if (kb < 7) {
      wpre0 = *(const float4*)(wbase + (size_t)((kb + 1) * 16 + wr) * 4608 + wc4 * 4);
      wpre1 = *(const float4*)(wbase + (size_t)((kb + 1) * 16 + wr + 8) * 4608 + wc4 * 4);
      apre  = *(const float4*)(aptr + (kb + 1) * 16);
    }
#pragma unroll
    for (int k = 0; k < 16; ++k) {
      float4 av  = *(const float4*)&a_s[cur][k][n0];
      float4 w0  = *(const float4*)&w_s[cur][k][tx * 4];
      float4 w1v = *(const float4*)&w_s[cur][k][64 + tx * 4];
#pragma unroll
      for (int i = 0; i < 4; ++i) {
        float a = (i == 0) ? av.x : (i == 1) ? av.y : (i == 2) ? av.z : av.w;
        acc[i][0] = fmaf(a, w0.x,  acc[i][0]);
        acc[i][1] = fmaf(a, w0.y,  acc[i][1]);
        acc[i][2] = fmaf(a, w0.z,  acc[i][2]);
        acc[i][3] = fmaf(a, w0.w,  acc[i][3]);
        acc[i][4] = fmaf(a, w1v.x, acc[i][4]);
        acc[i][5] = fmaf(a, w1v.y, acc[i][5]);
        acc[i][6] = fmaf(a, w1v.z, acc[i][6]);
        acc[i][7] = fmaf(a, w1v.w, acc[i][7]);
      }
    }
    if (kb < 7) {
      int nxt = cur ^ 1;
      *(float4*)&w_s[nxt][wr][wc4 * 4]     = wpre0;
      *(float4*)&w_s[nxt][wr + 8][wc4 * 4] = wpre1;
      a_s[nxt][aq * 4 + 0][anode] = apre.x;
      a_s[nxt][aq * 4 + 1][anode] = apre.y;
      a_s[nxt][aq * 4 + 2][anode] = apre.z;
      a_s[nxt][aq * 4 + 3][anode] = apre.w;
    }
    __syncthreads();
  }

  {
    const float* bp = b2 + cc * 128 + tx * 4;
    float4 bq0 = *(const float4*)(bp + 0);
    float4 bq1 = *(const float4*)(bp + 64);
#pragma unroll
    for (int i = 0; i < 4; ++i) {
      acc[i][0] += bq0.x; acc[i][1] += bq0.y; acc[i][2] += bq0.z; acc[i][3] += bq0.w;
      acc[i][4] += bq1.x; acc[i][5] += bq1.y; acc[i][6] += bq1.z; acc[i][7] += bq1.w;
    }
  }

  if (cc < 24) {
    int txh = tx >> 3;
#pragma unroll
    for (int i = 0; i < 4; ++i) {
      const float* cfp = coef_glob + (size_t)(nbase + n0 + i) * 192 + cc * 4 + txh;
      float cf0 = cfp[0];
      float cf1 = cfp[2];
      float* dst = acc_glob + (size_t)(nbase + n0 + i) * ACCW + (tx & 7) * 4;
#pragma unroll
      for (int e = 0; e < 4; ++e) {
        float v = acc[i][e] * cf0 + acc[i][4 + e] * cf1;
        v += __shfl_xor(v, 8);
        if (tx < 8) atomicAdd(&dst[e], v);
      }
    }
  } else if (cc < 32) {
    int txq = tx >> 2;
#pragma unroll
    for (int i = 0; i < 4; ++i) {
      const float* cfp = coef_glob + (size_t)(nbase + n0 + i) * 192 + (cc - 24) * 8 + txq;
      float cf0 = cfp[0];
      float cf1 = cfp[4];
      float* dst = acc_glob + (size_t)(nbase + n0 + i) * ACCW + 32 + (tx & 3) * 4;
#pragma unroll
      for (int e = 0; e < 4; ++e) {
        float v = acc[i][e] * cf0 + acc[i][4 + e] * cf1;
        v += __shfl_xor(v, 4);
        v += __shfl_xor(v, 8);
        if (tx < 4) atomicAdd(&dst[e], v);
      }
    }
  } else {
    int txq = tx >> 2;
#pragma unroll
    for (int i = 0; i < 4; ++i) {
      const float* cfp = coef_glob + (size_t)(nbase + n0 + i) * 192 + 96 +
                         ((cc - 32) * 8 + txq) * 3;
      float* dstb = acc_glob + (size_t)(nbase + n0 + i) * ACCW + 48 + (tx & 3) * 4;
#pragma unroll
      for (int comp = 0; comp < 3; ++comp) {
        float cf0 = cfp[comp];
        float cf1 = cfp[12 + comp];
#pragma unroll
        for (int e = 0; e < 4; ++e) {
          float v = acc[i][e] * cf0 + acc[i][4 + e] * cf1;
          v += __shfl_xor(v, 4);
          v += __shfl_xor(v, 8);
          if (tx < 4) atomicAdd(&dstb[comp * 16 + e], v);
        }
      }
    }
  }
}

// ---------------- combine 96 slots/node -> v_abs[b][80] ----------------
__global__ void k_combine(const int* __restrict__ count, const float* __restrict__ acc_glob,
                          const float* __restrict__ meta_f, const int* __restrict__ meta_b,
                          float* vabs) {
  int g = blockIdx.x * 256 + threadIdx.x;
  int pos = g / ACCW, slot = g - pos * ACCW;
  if (pos >= *count) return;
  const float* acc = acc_glob + (size_t)pos * ACCW;
  float sc = meta_f[pos * 4 + 3] * 0.10206207261596577f;  // gate*env / sqrt(96)
  float* vb = vabs + meta_b[pos] * 80;
  if (slot < 32) {
    atomicAdd(&vb[slot], acc[slot] * sc);
  } else if (slot < 48) {
    int o = slot - 32;
    float q = acc[slot] * sc;
    atomicAdd(&vb[32 + o * 3 + 0], q * meta_f[pos * 4 + 0]);
    atomicAdd(&vb[32 + o * 3 + 1], q * meta_f[pos * 4 + 1]);
    atomicAdd(&vb[32 + o * 3 + 2], q * meta_f[pos * 4 + 2]);
  } else {
    int s2 = slot - 48;          // comp*16 + o
    int comp = s2 >> 4, o = s2 & 15;
    atomicAdd(&vb[32 + o * 3 + comp], acc[slot] * sc);
  }
}

// ---------------- edge-feature scales -> scale_full[512][80] ----------------
__global__ void k_scales(const float* __restrict__ e_feat,
                         const float* __restrict__ we1, const float* __restrict__ be1,
                         const float* __restrict__ we2, const float* __restrict__ be2,
                         float* sfull) {
  int row = blockIdx.x;  // 512
  int t = threadIdx.x;   // 128
  __shared__ float hid[128];
  const float* ef = e_feat + row * 16;
  float s = be1[t];
  for (int k = 0; k < 16; ++k) s = fmaf(ef[k], we1[k * 128 + t], s);
  hid[t] = silu_f(s);
  __syncthreads();
  if (t < 48) {
    float o = be2[t];
    for (int k = 0; k < 128; ++k) o = fmaf(hid[k], we2[k * 48 + t], o);
    if (t < 32) sfull[row * 80 + t] = o;
    else {
      int oo = t - 32;
      sfull[row * 80 + 32 + oo * 3 + 0] = o;
      sfull[row * 80 + 32 + oo * 3 + 1] = o;
      sfull[row * 80 + 32 + oo * 3 + 2] = o;
    }
  }
}

// ---------------- head G1: build inv + (32768x48)@wo1 + silu -> xh/xl (bf16 hi/lo) ----------------
// Block: 64 rows x 128 cols, K=48 (single LDS tile; w1 24 KB + invt 12 KB).
__global__ __launch_bounds__(256) void k_hg1(const float* __restrict__ vabs,
                                             const float* __restrict__ sfull,
                                             const float* __restrict__ wo1,
                                             const float* __restrict__ bo1,
                                             __bf16* __restrict__ xh,
                                             __bf16* __restrict__ xl) {
  int rbase = blockIdx.x * 64;   // 512 blocks
  int b = rbase >> 9;
  int e0 = rbase & 511;
  int t = threadIdx.x;
  int tx = t & 15, ty = t >> 4;
  int n0 = ty * 4;

  __shared__ float w_s[48 * 128];   // [k][col], 24 KB
  __shared__ float invt[48][64];    // [k][row], 12 KB
  __shared__ float va[80];

  if (t < 80) va[t] = vabs[b * 80 + t];
  {
    const float4* wg = (const float4*)wo1;
    float4* ws4 = (float4*)w_s;
#pragma unroll
    for (int it = 0; it < 6; ++it) ws4[t + it * 256] = wg[t + it * 256];
  }
  __syncthreads();

  // inv transposed [c][row]: 48*64 elems, 12 per thread
  for (int idx = t; idx < 48 * 64; idx += 256) {
    int cd = idx >> 6, r = idx & 63;
    const float* sf = sfull + (size_t)(e0 + r) * 80;
    float v;
    if (cd < 32) v = va[cd] * sf[cd];
    else {
      int base = 32 + (cd - 32) * 3;
      float m0 = va[base + 0] * sf[base + 0];
      float m1 = va[base + 1] * sf[base + 1];
      float m2 = va[base + 2] * sf[base + 2];
      v = sqrtf(m0 * m0 + m1 * m1 + m2 * m2 + 1e-12f);
    }
    invt[cd][r] = v;
  }
  __syncthreads();

  float acc[4][8];
#pragma unroll
  for (int i = 0; i < 4; ++i)
#pragma unroll
    for (int j = 0; j < 8; ++j) acc[i][j] = 0.f;

  for (int k = 0; k < 48; ++k) {
    float4 av  = *(const float4*)&invt[k][n0];
    float4 w0  = *(const float4*)&w_s[k * 128 + tx * 4];
    float4 w1v = *(const float4*)&w_s[k * 128 + 64 + tx * 4];
#pragma unroll
    for (int i = 0; i < 4; ++i) {
      float a = (i == 0) ? av.x : (i == 1) ? av.y : (i == 2) ? av.z : av.w;
      acc[i][0] = fmaf(a, w0.x,  acc[i][0]);
      acc[i][1] = fmaf(a, w0.y,  acc[i][1]);
      acc[i][2] = fmaf(a, w0.z,  acc[i][2]);
      acc[i][3] = fmaf(a, w0.w,  acc[i][3]);
      acc[i][4] = fmaf(a, w1v.x, acc[i][4]);
      acc[i][5] = fmaf(a, w1v.y, acc[i][5]);
      acc[i][6] = fmaf(a, w1v.z, acc[i][6]);
      acc[i][7] = fmaf(a, w1v.w, acc[i][7]);
    }
  }

  float4 bq0 = *(const float4*)(bo1 + tx * 4);
  float4 bq1 = *(const float4*)(bo1 + 64 + tx * 4);
#pragma unroll
  for (int i = 0; i < 4; ++i) {
    size_t row = (size_t)(rbase + n0 + i);
    float q0[4] = {silu_f(acc[i][0] + bq0.x), silu_f(acc[i][1] + bq0.y),
                   silu_f(acc[i][2] + bq0.z), silu_f(acc[i][3] + bq0.w)};
    float q1[4] = {silu_f(acc[i][4] + bq1.x), silu_f(acc[i][5] + bq1.y),
                   silu_f(acc[i][6] + bq1.z), silu_f(acc[i][7] + bq1.w)};
    union { __bf16 bb[4]; uint2 u; } H, L;
#pragma unroll
    for (int e = 0; e < 4; ++e) {
      __bf16 hv = (__bf16)q0[e];
      H.bb[e] = hv;
      L.bb[e] = (__bf16)(q0[e] - (float)hv);
    }
    *(uint2*)(xh + row * 128 + tx * 4) = H.u;
    *(uint2*)(xl + row * 128 + tx * 4) = L.u;
#pragma unroll
    for (int e = 0; e < 4; ++e) {
      __bf16 hv = (__bf16)q1[e];
      H.bb[e] = hv;
      L.bb[e] = (__bf16)(q1[e] - (float)hv);
    }
    *(uint2*)(xh + row * 128 + 64 + tx * 4) = H.u;
    *(uint2*)(xl + row * 128 + 64 + tx * 4) = L.u;
  }
}

// ---------------- split-bf16 MFMA GEMM for head layers 2/3 ----------------
// C = A @ B^T_layout + bias, A: [32768][128] as hi/lo bf16 planes (row-major),
// B: [ncols][128] hi/lo bf16 ([n][k], from k_wprep). fp32-accurate via
// (ah+al)(bh+bl) ~= ah*bh + al*bh + ah*bl (lo*lo ~ 2^-16 dropped).
// Block: 64 rows x 128 cols; wave w owns M-tile w (16 rows), all 8 N-tiles.
// LDS frag-major slots (base + 16B*lane) -> linear, conflict-free b128.
// MODE 0 (hg2): silu, write hi/lo bf16 in-place (block fully consumes its own
//               rows before epilogue -> in-place safe). MODE 1 (hg3): +bias,
//               write f32 to out[.][256] at col offset blockIdx.x*128.
template<int MODE>
__global__ __launch_bounds__(256) void k_mgemm(
    const __bf16* Ah, const __bf16* Al,
    const __bf16* __restrict__ Bh, const __bf16* __restrict__ Bl,
    const float* __restrict__ bias,
    __bf16* Oh, __bf16* Ol, float* __restrict__ Of) {
  int rbase = blockIdx.y * 64;
  int cbase = blockIdx.x * 128;
  int t = threadIdx.x;
  int w = t >> 6;            // wave = M-tile
  int l = t & 63;
  int kg = l >> 4, ln = l & 15;

  __shared__ v8bf As[2][2][4][64];   // [buf][plane][mt][lane]  16 KB
  __shared__ v8bf Bs[2][2][8][64];   // [buf][plane][nt][lane]  32 KB

  // fragment source addresses (element units); 8 consecutive k per lane
  size_t arow  = (size_t)(rbase + w * 16 + ln) * 128 + kg * 8;
  int nt0 = w, nt1 = w + 4;
  size_t brow0 = (size_t)(cbase + nt0 * 16 + ln) * 128 + kg * 8;
  size_t brow1 = (size_t)(cbase + nt1 * 16 + ln) * 128 + kg * 8;

  v8bf ra0, ra1, rb0, rb1, rb2, rb3;
  ra0 = *(const v8bf*)(Ah + arow);
  ra1 = *(const v8bf*)(Al + arow);
  rb0 = *(const v8bf*)(Bh + brow0);
  rb1 = *(const v8bf*)(Bh + brow1);
  rb2 = *(const v8bf*)(Bl + brow0);
  rb3 = *(const v8bf*)(Bl + brow1);
  As[0][0][w][l]   = ra0;
  As[0][1][w][l]   = ra1;
  Bs[0][0][nt0][l] = rb0;
  Bs[0][0][nt1][l] = rb1;
  Bs[0][1][nt0][l] = rb2;
  Bs[0][1][nt1][l] = rb3;
  __syncthreads();

  v4f acc[8];
  v4f z4 = {0.f, 0.f, 0.f, 0.f};
#pragma unroll
  for (int i = 0; i < 8; ++i) acc[i] = z4;

  for (int kb = 0; kb < 4; ++kb) {
    int cur = kb & 1;
    if (kb < 3) {
      int off = (kb + 1) * 32;
      ra0 = *(const v8bf*)(Ah + arow + off);
      ra1 = *(const v8bf*)(Al + arow + off);
      rb0 = *(const v8bf*)(Bh + brow0 + off);
      rb1 = *(const v8bf*)(Bh + brow1 + off);
      rb2 = *(const v8bf*)(Bl + brow0 + off);
      rb3 = *(const v8bf*)(Bl + brow1 + off);
    }
    v8bf ah  = As[cur][0][w][l];
    v8bf alo = As[cur][1][w][l];
#pragma unroll
    for (int nt = 0; nt < 8; ++nt) {
      v8bf bh = Bs[cur][0][nt][l];
      v8bf bl = Bs[cur][1][nt][l];
      acc[nt] = __builtin_amdgcn_mfma_f32_16x16x32_bf16(ah,  bh, acc[nt], 0, 0, 0);
      acc[nt] = __builtin_amdgcn_mfma_f32_16x16x32_bf16(alo, bh, acc[nt], 0, 0, 0);
      acc[nt] = __builtin_amdgcn_mfma_f32_16x16x32_bf16(ah,  bl, acc[nt], 0, 0, 0);
    }
    if (kb < 3) {
      int nxt = cur ^ 1;
      As[nxt][0][w][l]   = ra0;
      As[nxt][1][w][l]   = ra1;
      Bs[nxt][0][nt0][l] = rb0;
      Bs[nxt][0][nt1][l] = rb1;
      Bs[nxt][1][nt0][l] = rb2;
      Bs[nxt][1][nt1][l] = rb3;
    }
    __syncthreads();
  }

  // epilogue; D layout: col = lane&15 (within N-tile), row = (lane>>4)*4 + reg
  int r0 = rbase + w * 16 + kg * 4;
#pragma unroll
  for (int nt = 0; nt < 8; ++nt) {
    float bv = bias[cbase + nt * 16 + ln];
#pragma unroll
    for (int j = 0; j < 4; ++j) {
      float x = acc[nt][j] + bv;
      if (MODE == 0) {
        x = silu_f(x);
        __bf16 hv = (__bf16)x;
        size_t o = (size_t)(r0 + j) * 128 + nt * 16 + ln;
        Oh[o] = hv;
        Ol[o] = (__bf16)(x - (float)hv);
      } else {
        Of[(size_t)(r0 + j) * 256 + cbase + nt * 16 + ln] = x;
      }
    }
  }
}

extern "C" void kernel_launch(void* const* d_in, const int* in_sizes, int n_in,
                              void* d_out, int out_size, void* d_ws, size_t ws_size,
                              hipStream_t stream) {
  const float* h        = (const float*)d_in[0];
  const float* h_full   = (const float*)d_in[1];
  const int*   z        = (const int*)d_in[2];
  const float* e_feat   = (const float*)d_in[4];
  const int*   abs_idx  = (const int*)d_in[5];
  const int*   att_dst  = (const int*)d_in[6];
  const float* att_dist = (const float*)d_in[7];
  const float* att_vec  = (const float*)d_in[8];
  const float* w_zemb   = (const float*)d_in[9];
  const float* w1_rad   = (const float*)d_in[10];
  const float* b1_rad   = (const float*)d_in[11];
  const float* w2_rad   = (const float*)d_in[12];
  const float* b2_rad   = (const float*)d_in[13];
  const float* wg1      = (const float*)d_in[14];
  const float* bg1      = (const float*)d_in[15];
  const float* wg2      = (const float*)d_in[16];
  const float* bg2      = (const float*)d_in[17];
  const float* we1      = (const float*)d_in[18];
  const float* be1      = (const float*)d_in[19];
  const float* we2      = (const float*)d_in[20];
  const float* be2      = (const float*)d_in[21];
  const float* wo1      = (const float*)d_in[22];
  const float* bo1      = (const float*)d_in[23];
  const float* wo2      = (const float*)d_in[24];
  const float* bo2      = (const float*)d_in[25];
  const float* wo3      = (const float*)d_in[26];
  const float* bo3      = (const float*)d_in[27];
  float* out = (float*)d_out;

  // workspace layout (~17.3 MB): persistent small buffers first, then a
  // region where phase-1 (a/coef/acc, 6.8 MB) and phase-2 (xh+xl, 16 MB) alias.
  float* meta_f  = (float*)d_ws;                 // MAXACT*4
  float* vabs    = meta_f + MAXACT * 4;          // 64*80
  float* sfull   = vabs + NB * OD_;              // 512*80
  float* habs_g  = sfull + NE_ * OD_;            // 64*128
  __bf16* w2t_h  = (__bf16*)(habs_g + NB * 128); // 128*128 bf16
  __bf16* w2t_l  = w2t_h + 128 * 128;
  __bf16* w3t_h  = w2t_l + 128 * 128;            // 256*128 bf16
  __bf16* w3t_l  = w3t_h + 256 * 128;
  int* widx   = (int*)(w3t_l + 256 * 128);       // 8192
  int* active = widx + FLAT;                     // 4096
  int* meta_b = active + MAXACT;                 // 4096
  int* count  = meta_b + MAXACT;                 // 1 (+pad to 16B)
  float* big  = (float*)(count + 15);            // aligned big region
  float* a_glob    = big;                        // MAXACT*128   (phase 1)
  float* coef_glob = a_glob + MAXACT * 128;      // MAXACT*192   (phase 1)
  float* acc_glob  = coef_glob + MAXACT * 192;   // MAXACT*96    (phase 1)
  __bf16* xh       = (__bf16*)big;               // 32768*128    (phase 2, aliases)
  __bf16* xl       = xh + (size_t)32768 * 128;   // 32768*128

  k_init<<<1536, 256, 0, stream>>>(acc_glob, vabs, widx, count);
  k_wprep<<<384, 128, 0, stream>>>(wo2, wo3, w2t_h, w2t_l, w3t_h, w3t_l);
  k_scatter<<<16, 256, 0, stream>>>(att_dst, widx);
  k_build<<<32, 256, 0, stream>>>(widx, active, count);
  k_gabs<<<NB, 128, 0, stream>>>(abs_idx, h, wg1, habs_g);
  k_node<<<MAXACT, 128, 0, stream>>>(count, active, widx, att_dist, att_vec, z, w_zemb,
                                     abs_idx, w1_rad, b1_rad, h, habs_g, wg1, bg1, wg2, bg2,
                                     h_full, a_glob, coef_glob, meta_f, meta_b);
  k_rgemm<<<dim3(36, 64), 256, 0, stream>>>(count, a_glob, coef_glob, w2_rad, b2_rad,
                                            acc_glob);
  k_combine<<<1536, 256, 0, stream>>>(count, acc_glob, meta_f, meta_b, vabs);
  k_scales<<<512, 128, 0, stream>>>(e_feat, we1, be1, we2, be2, sfull);
  k_hg1<<<512, 256, 0, stream>>>(vabs, sfull, wo1, bo1, xh, xl);
  k_mgemm<0><<<dim3(1, 512), 256, 0, stream>>>(xh, xl, w2t_h, w2t_l, bo2,
                                               xh, xl, nullptr);
  k_mgemm<1><<<dim3(2, 512), 256, 0, stream>>>(xh, xl, w3t_h, w3t_l, bo3,
                                               nullptr, nullptr, out);
}

// Round 2
// 257.157 us; speedup vs baseline: 1.2119x; 1.1721x over previous
//
#include <hip/hip_runtime.h>
#include <math.h>

#define FLAT   8192
#define NB     64
#define OD_    80
#define NE_    512
#define EATT_  4096
#define MAXACT 4096
// acc_glob: 96 floats/node, atomically accumulated by k_mrgemm:
//   [0..31]  out_s partial (pre gate/env/norm)
//   [32..47] q (scalar coeff that multiplies yv)
//   [48..95] D-term out_v, layout comp*16 + o
#define ACCW 96

typedef __bf16 v8bf __attribute__((ext_vector_type(8)));
typedef float  v4f  __attribute__((ext_vector_type(4)));

__device__ __forceinline__ float silu_f(float x) { return x / (1.f + __expf(-x)); }
__device__ __forceinline__ float sigm_f(float x) { return 1.f / (1.f + __expf(-x)); }

// ---------------- init: zero acc + vabs, widx=-1, count=0 ----------------
__global__ void k_init(float* acc, float* vabs, int* widx, int* count) {
  int t = blockIdx.x * 256 + threadIdx.x;
  if (t < MAXACT * ACCW) acc[t] = 0.f;
  if (t < FLAT) widx[t] = -1;
  if (t < NB * OD_) vabs[t] = 0.f;
  if (t == 0) *count = 0;
}

// ---------------- scatter: last-write-wins == max edge index ----------------
__global__ void k_scatter(const int* __restrict__ att_dst, int* widx) {
  int i = blockIdx.x * 256 + threadIdx.x;
  if (i < EATT_) atomicMax(&widx[att_dst[i]], i);
}

// ---------------- compact active-node list ----------------
__global__ void k_build(const int* __restrict__ widx, int* active, int* count) {
  int j = blockIdx.x * 256 + threadIdx.x;
  if (j < FLAT && widx[j] >= 0) {
    int p = atomicAdd(count, 1);
    active[p] = j;
  }
}

// ---------------- per-batch absorber row of gate layer 1: h_abs @ wg1 ----------------
__global__ void k_gabs(const int* __restrict__ abs_idx, const float* __restrict__ h,
                       const float* __restrict__ wg1, float* habs_g) {
  int b = blockIdx.x;   // 64
  int t = threadIdx.x;  // 128
  __shared__ float hs[128];
  int nabs = abs_idx[b];
  hs[t] = h[(size_t)(b * 128 + nabs) * 128 + t];
  __syncthreads();
  float g = 0.f;
  for (int c = 0; c < 128; ++c) g = fmaf(hs[c], wg1[c * 128 + t], g);
  habs_g[b * 128 + t] = g;
}

// ---------------- transpose+split head weights to bf16 hi/lo, [n][k] ----------------
// wo2: [128k][128n] -> w2t_{h,l}[128n][128k]; wo3: [128k][256n] -> w3t[256n][128k]
__global__ void k_wprep(const float* __restrict__ wo2, const float* __restrict__ wo3,
                        __bf16* w2h, __bf16* w2l, __bf16* w3h, __bf16* w3l) {
  int b = blockIdx.x;   // 0..383
  int t = threadIdx.x;  // 128 = k index
  if (b < 128) {
    float v = wo2[t * 128 + b];
    __bf16 h = (__bf16)v;
    w2h[b * 128 + t] = h;
    w2l[b * 128 + t] = (__bf16)(v - (float)h);
  } else {
    int n = b - 128;
    float v = wo3[t * 256 + n];
    __bf16 h = (__bf16)v;
    w3h[n * 128 + t] = h;
    w3l[n * 128 + t] = (__bf16)(v - (float)h);
  }
}

// ---------------- transpose+split radial weights: w2_rad [128k][4608n] -> [n][k] hi/lo ----
__global__ void k_wprep2(const float* __restrict__ w2, __bf16* wh, __bf16* wl) {
  int n = blockIdx.x * 32 + (threadIdx.x >> 3);   // 144 blocks -> n in 0..4607
  int k0 = (threadIdx.x & 7) * 16;
  union { __bf16 b[16]; uint4 u[2]; } H, L;
#pragma unroll
  for (int kk = 0; kk < 16; ++kk) {
    float v = w2[(size_t)(k0 + kk) * 4608 + n];
    __bf16 hv = (__bf16)v;
    H.b[kk] = hv;
    L.b[kk] = (__bf16)(v - (float)hv);
  }
  *(uint4*)(wh + (size_t)n * 128 + k0)     = H.u[0];
  *(uint4*)(wh + (size_t)n * 128 + k0 + 8) = H.u[1];
  *(uint4*)(wl + (size_t)n * 128 + k0)     = L.u[0];
  *(uint4*)(wl + (size_t)n * 128 + k0 + 8) = L.u[1];
}

// ---------------- per active node: rbf, hidden a(128) as bf16 hi/lo, gate, env, coefs ----
__global__ void k_node(const int* __restrict__ count, const int* __restrict__ active,
                       const int* __restrict__ widx,
                       const float* __restrict__ att_dist, const float* __restrict__ att_vec,
                       const int* __restrict__ z, const float* __restrict__ w_zemb,
                       const int* __restrict__ abs_idx,
                       const float* __restrict__ w1_rad, const float* __restrict__ b1_rad,
                       const float* __restrict__ h, const float* __restrict__ habs_g,
                       const float* __restrict__ wg1, const float* __restrict__ bg1,
                       const float* __restrict__ wg2, const float* __restrict__ bg2,
                       const float* __restrict__ h_full,
                       __bf16* ah_glob, __bf16* al_glob,
                       float* coef_glob, float* meta_f, int* meta_b) {
  int pos = blockIdx.x;
  if (pos >= *count) return;
  int t = threadIdx.x;  // 128 threads
  __shared__ float win[49];
  __shared__ float yv_s[3];
  __shared__ float red[128];
  __shared__ float sh_d;

  int j = active[pos];
  int b = j >> 7;
  int n = j & 127;
  int e = widx[j];

  if (t == 0) {
    float d = att_dist[e];
    sh_d = d;
    float eps = fmaxf(d, 1e-8f);
    const float s3 = 1.7320508075688772f;
    yv_s[0] = s3 * att_vec[e * 3 + 0] / eps;
    yv_s[1] = s3 * att_vec[e * 3 + 1] / eps;
    yv_s[2] = s3 * att_vec[e * 3 + 2] / eps;
  }
  int nabs = abs_idx[b];
  float isab = (n == nabs) ? 1.f : 0.f;
  if (t < 32) win[t] = w_zemb[z[j] * 32 + t];
  if (t == 32) win[32] = isab;
  if (t >= 33 && t < 49) {
    int k = t - 33;
    float d = att_dist[e];
    float x = (d - (float)k * (1.f / 3.f)) * 3.f;  // width = CUTOFF/(RBF-1) = 1/3
    win[t] = __expf(-0.5f * x * x);
  }
  __syncthreads();

  // hidden a = silu(win @ w1_rad + b1_rad)   (49 -> 128), stored as bf16 hi/lo
  {
    float s = b1_rad[t];
    for (int k = 0; k < 49; ++k) s = fmaf(win[k], w1_rad[k * 128 + t], s);
    float av = silu_f(s);
    __bf16 hv = (__bf16)av;
    ah_glob[pos * 128 + t] = hv;
    al_glob[pos * 128 + t] = (__bf16)(av - (float)hv);
  }

  // gate MLP hidden (273 -> 128); h_abs part precomputed per-batch (k_gabs)
  {
    float g = bg1[t] + habs_g[b * 128 + t];
    const float* hn = h + (size_t)j * 128;
    for (int c = 0; c < 128; ++c) g = fmaf(hn[c], wg1[(128 + c) * 128 + t], g);
    for (int k = 0; k < 16; ++k)  g = fmaf(win[33 + k], wg1[(256 + k) * 128 + t], g);
    g = fmaf(isab, wg1[272 * 128 + t], g);
    red[t] = silu_f(g) * wg2[t];
  }
  __syncthreads();

  // per-node contraction coefficients: [s1(64), p*inv_s3(32), v1(96)]
  const float* hf = h_full + (size_t)j * 160;
  if (t < 64) coef_glob[pos * 192 + t] = hf[t];
  if (t >= 64 && t < 96) {
    int i = t - 64;
    float pv = hf[64 + i * 3 + 0] * yv_s[0] + hf[64 + i * 3 + 1] * yv_s[1] +
               hf[64 + i * 3 + 2] * yv_s[2];
    coef_glob[pos * 192 + t] = pv * 0.5773502691896258f;
  }
  if (t < 96) coef_glob[pos * 192 + 96 + t] = hf[64 + t];

  if (t == 0) {
    float tot = 0.f;
    for (int k = 0; k < 128; ++k) tot += red[k];
    tot += bg2[0];
    float gate = sigm_f(tot);
    float d = sh_d;
    float env = (d < 5.f) ? 0.5f * (__cosf(3.14159265358979323846f * d * 0.2f) + 1.f) : 0.f;
    meta_f[pos * 4 + 0] = yv_s[0];
    meta_f[pos * 4 + 1] = yv_s[1];
    meta_f[pos * 4 + 2] = yv_s[2];
    meta_f[pos * 4 + 3] = gate * env;
    meta_b[pos] = b;
  }
}

// ---------------- split-bf16 MFMA radial GEMM + fused contraction ----------------
// tpw = a[node][128k] @ w2rt[4608n][128k]^T + b2, contracted on the fly into
// acc_glob[node][96]. Block = 128 nodes x 128 cols; 4 waves; wave w owns
// M-tiles {2w, 2w+1} x all 8 N-tiles (each B-fragment LDS read feeds 2 M-tiles).
// A fragments go global->reg directly. MFMA C layout: col=ln, row=kg*4+reg.
// Column->coef mapping (chunk cc of 128 cols):
//   cc<24 (wA/wB): i_local = nt>>1, o = (nt&1)*16+ln, coef[cc*4 + i_local]
//   cc<32 (wC):    i = (cc-24)*8+nt, o = ln, coef[i]        -> slot 32+o
//   else  (wD):    i = (cc-32)*8+nt, o = ln, coef[96+i*3+c] -> slot 48+c*16+o
__global__ __launch_bounds__(256) void k_mrgemm(
    const int* __restrict__ count,
    const __bf16* Ah, const __bf16* Al,
    const __bf16* __restrict__ Bh, const __bf16* __restrict__ Bl,
    const float* __restrict__ b2, const float* __restrict__ coef_glob,
    float* __restrict__ acc_glob) {
  int cc = blockIdx.x;            // 0..35
  int nbase = blockIdx.y * 128;   // 32 y-blocks
  int cnt = *count;
  if (nbase >= cnt) return;
  int t = threadIdx.x;
  int w = t >> 6, l = t & 63;
  int kg = l >> 4, ln = l & 15;
  int cbase = cc * 128;

  __shared__ v8bf Bs[2][2][8][64];   // [buf][plane][nt][lane] 32 KB

  size_t brow0 = (size_t)(cbase + w * 16 + ln) * 128 + kg * 8;
  size_t brow1 = (size_t)(cbase + (w + 4) * 16 + ln) * 128 + kg * 8;
  size_t arow0 = (size_t)(nbase + (2 * w) * 16 + ln) * 128 + kg * 8;
  size_t arow1 = (size_t)(nbase + (2 * w + 1) * 16 + ln) * 128 + kg * 8;

  v8bf rb0 = *(const v8bf*)(Bh + brow0);
  v8bf rb1 = *(const v8bf*)(Bh + brow1);
  v8bf rb2 = *(const v8bf*)(Bl + brow0);
  v8bf rb3 = *(const v8bf*)(Bl + brow1);
  v8bf ah0 = *(const v8bf*)(Ah + arow0);
  v8bf al0 = *(const v8bf*)(Al + arow0);
  v8bf ah1 = *(const v8bf*)(Ah + arow1);
  v8bf al1 = *(const v8bf*)(Al + arow1);
  Bs[0][0][w][l]     = rb0;
  Bs[0][0][w + 4][l] = rb1;
  Bs[0][1][w][l]     = rb2;
  Bs[0][1][w + 4][l] = rb3;
  __syncthreads();

  v4f acc[2][8];
  v4f z4 = {0.f, 0.f, 0.f, 0.f};
#pragma unroll
  for (int i = 0; i < 2; ++i)
#pragma unroll
    for (int j = 0; j < 8; ++j) acc[i][j] = z4;

  for (int kb = 0; kb < 4; ++kb) {
    int cur = kb & 1;
    v8bf nb0, nb1, nb2, nb3, nh0, nl0, nh1, nl1;
    if (kb < 3) {
      int off = (kb + 1) * 32;
      nb0 = *(const v8bf*)(Bh + brow0 + off);
      nb1 = *(const v8bf*)(Bh + brow1 + off);
      nb2 = *(const v8bf*)(Bl + brow0 + off);
      nb3 = *(const v8bf*)(Bl + brow1 + off);
      nh0 = *(const v8bf*)(Ah + arow0 + off);
      nl0 = *(const v8bf*)(Al + arow0 + off);
      nh1 = *(const v8bf*)(Ah + arow1 + off);
      nl1 = *(const v8bf*)(Al + arow1 + off);
    }
#pragma unroll
    for (int nt = 0; nt < 8; ++nt) {
      v8bf bh = Bs[cur][0][nt][l];
      v8bf bl = Bs[cur][1][nt][l];
      acc[0][nt] = __builtin_amdgcn_mfma_f32_16x16x32_bf16(ah0, bh, acc[0][nt], 0, 0, 0);
      acc[0][nt] = __builtin_amdgcn_mfma_f32_16x16x32_bf16(al0, bh, acc[0][nt], 0, 0, 0);
      acc[0][nt] = __builtin_amdgcn_mfma_f32_16x16x32_bf16(ah0, bl, acc[0][nt], 0, 0, 0);
      acc[1][nt] = __builtin_amdgcn_mfma_f32_16x16x32_bf16(ah1, bh, acc[1][nt], 0, 0, 0);
      acc[1][nt] = __builtin_amdgcn_mfma_f32_16x16x32_bf16(al1, bh, acc[1][nt], 0, 0, 0);
      acc[1][nt] = __builtin_amdgcn_mfma_f32_16x16x32_bf16(ah1, bl, acc[1][nt], 0, 0, 0);
    }
    if (kb < 3) {
      int nxt = cur ^ 1;
      Bs[nxt][0][w][l]     = nb0;
      Bs[nxt][0][w + 4][l] = nb1;
      Bs[nxt][1][w][l]     = nb2;
      Bs[nxt][1][w + 4][l] = nb3;
      ah0 = nh0; al0 = nl0; ah1 = nh1; al1 = nl1;
    }
    __syncthreads();
  }

  // bias (tpw-layer bias, added before contraction — linear, so per-element)
  float b2v[8];
#pragma unroll
  for (int nt = 0; nt < 8; ++nt) b2v[nt] = b2[cbase + nt * 16 + ln];

#pragma unroll
  for (int mi = 0; mi < 2; ++mi) {
    int nodeb = nbase + (2 * w + mi) * 16 + kg * 4;
#pragma unroll
    for (int j = 0; j < 4; ++j) {
      int nd = nodeb + j;
      if (nd >= cnt) continue;
      float* dst = acc_glob + (size_t)nd * ACCW;
      const float* cf = coef_glob + (size_t)nd * 192;
      if (cc < 24) {
        float s0 = 0.f, s1 = 0.f;
#pragma unroll
        for (int m = 0; m < 4; ++m) {
          float c = cf[cc * 4 + m];
          s0 = fmaf(acc[mi][2 * m][j] + b2v[2 * m], c, s0);
          s1 = fmaf(acc[mi][2 * m + 1][j] + b2v[2 * m + 1], c, s1);
        }
        atomicAdd(&dst[ln], s0);
        atomicAdd(&dst[16 + ln], s1);
      } else if (cc < 32) {
        float s = 0.f;
#pragma unroll
        for (int nt = 0; nt < 8; ++nt)
          s = fmaf(acc[mi][nt][j] + b2v[nt], cf[(cc - 24) * 8 + nt], s);
        atomicAdd(&dst[32 + ln], s);
      } else {
        float s0 = 0.f, s1 = 0.f, s2 = 0.f;
#pragma unroll
        for (int nt = 0; nt < 8; ++nt) {
          float x = acc[mi][nt][j] + b2v[nt];
          const float* c3 = cf + 96 + ((cc - 32) * 8 + nt) * 3;
          s0 = fmaf(x, c3[0], s0);
          s1 = fmaf(x, c3[1], s1);
          s2 = fmaf(x, c3[2], s2);
        }
        atomicAdd(&dst[48 + ln], s0);
        atomicAdd(&dst[48 + 16 + ln], s1);
        atomicAdd(&dst[48 + 32 + ln], s2);
      }
    }
  }
}

// ---------------- combine 96 slots/node -> v_abs[b][80] ----------------
__global__ void k_combine(const int* __restrict__ count, const float* __restrict__ acc_glob,
                          const float* __restrict__ meta_f, const int* __restrict__ meta_b,
                          float* vabs) {
  int g = blockIdx.x * 256 + threadIdx.x;
  int pos = g / ACCW, slot = g - pos * ACCW;
  if (pos >= *count) return;
  const float* acc = acc_glob + (size_t)pos * ACCW;
  float sc = meta_f[pos * 4 + 3] * 0.10206207261596577f;  // gate*env / sqrt(96)
  float* vb = vabs + meta_b[pos] * 80;
  if (slot < 32) {
    atomicAdd(&vb[slot], acc[slot] * sc);
  } else if (slot < 48) {
    int o = slot - 32;
    float q = acc[slot] * sc;
    atomicAdd(&vb[32 + o * 3 + 0], q * meta_f[pos * 4 + 0]);
    atomicAdd(&vb[32 + o * 3 + 1], q * meta_f[pos * 4 + 1]);
    atomicAdd(&vb[32 + o * 3 + 2], q * meta_f[pos * 4 + 2]);
  } else {
    int s2 = slot - 48;          // comp*16 + o
    int comp = s2 >> 4, o = s2 & 15;
    atomicAdd(&vb[32 + o * 3 + comp], acc[slot] * sc);
  }
}

// ---------------- edge-feature scales -> scale_full[512][80] ----------------
__global__ void k_scales(const float* __restrict__ e_feat,
                         const float* __restrict__ we1, const float* __restrict__ be1,
                         const float* __restrict__ we2, const float* __restrict__ be2,
                         float* sfull) {
  int row = blockIdx.x;  // 512
  int t = threadIdx.x;   // 128
  __shared__ float hid[128];
  const float* ef = e_feat + row * 16;
  float s = be1[t];
  for (int k = 0; k < 16; ++k) s = fmaf(ef[k], we1[k * 128 + t], s);
  hid[t] = silu_f(s);
  __syncthreads();
  if (t < 48) {
    float o = be2[t];
    for (int k = 0; k < 128; ++k) o = fmaf(hid[k], we2[k * 48 + t], o);
    if (t < 32) sfull[row * 80 + t] = o;
    else {
      int oo = t - 32;
      sfull[row * 80 + 32 + oo * 3 + 0] = o;
      sfull[row * 80 + 32 + oo * 3 + 1] = o;
      sfull[row * 80 + 32 + oo * 3 + 2] = o;
    }
  }
}

// ---------------- head G1: build inv + (32768x48)@wo1 + silu -> xh/xl (bf16 hi/lo) ----------------
__global__ __launch_bounds__(256) void k_hg1(const float* __restrict__ vabs,
                                             const float* __restrict__ sfull,
                                             const float* __restrict__ wo1,
                                             const float* __restrict__ bo1,
                                             __bf16* __restrict__ xh,
                                             __bf16* __restrict__ xl) {
  int rbase = blockIdx.x * 64;   // 512 blocks
  int b = rbase >> 9;
  int e0 = rbase & 511;
  int t = threadIdx.x;
  int tx = t & 15, ty = t >> 4;
  int n0 = ty * 4;

  __shared__ float w_s[48 * 128];   // [k][col], 24 KB
  __shared__ float invt[48][64];    // [k][row], 12 KB
  __shared__ float va[80];

  if (t < 80) va[t] = vabs[b * 80 + t];
  {
    const float4* wg = (const float4*)wo1;
    float4* ws4 = (float4*)w_s;
#pragma unroll
    for (int it = 0; it < 6; ++it) ws4[t + it * 256] = wg[t + it * 256];
  }
  __syncthreads();

  // inv transposed [c][row]: 48*64 elems, 12 per thread
  for (int idx = t; idx < 48 * 64; idx += 256) {
    int cd = idx >> 6, r = idx & 63;
    const float* sf = sfull + (size_t)(e0 + r) * 80;
    float v;
    if (cd < 32) v = va[cd] * sf[cd];
    else {
      int base = 32 + (cd - 32) * 3;
      float m0 = va[base + 0] * sf[base + 0];
      float m1 = va[base + 1] * sf[base + 1];
      float m2 = va[base + 2] * sf[base + 2];
      v = sqrtf(m0 * m0 + m1 * m1 + m2 * m2 + 1e-12f);
    }
    invt[cd][r] = v;
  }
  __syncthreads();

  float acc[4][8];
#pragma unroll
  for (int i = 0; i < 4; ++i)
#pragma unroll
    for (int j = 0; j < 8; ++j) acc[i][j] = 0.f;

  for (int k = 0; k < 48; ++k) {
    float4 av  = *(const float4*)&invt[k][n0];
    float4 w0  = *(const float4*)&w_s[k * 128 + tx * 4];
    float4 w1v = *(const float4*)&w_s[k * 128 + 64 + tx * 4];
#pragma unroll
    for (int i = 0; i < 4; ++i) {
      float a = (i == 0) ? av.x : (i == 1) ? av.y : (i == 2) ? av.z : av.w;
      acc[i][0] = fmaf(a, w0.x,  acc[i][0]);
      acc[i][1] = fmaf(a, w0.y,  acc[i][1]);
      acc[i][2] = fmaf(a, w0.z,  acc[i][2]);
      acc[i][3] = fmaf(a, w0.w,  acc[i][3]);
      acc[i][4] = fmaf(a, w1v.x, acc[i][4]);
      acc[i][5] = fmaf(a, w1v.y, acc[i][5]);
      acc[i][6] = fmaf(a, w1v.z, acc[i][6]);
      acc[i][7] = fmaf(a, w1v.w, acc[i][7]);
    }
  }

  float4 bq0 = *(const float4*)(bo1 + tx * 4);
  float4 bq1 = *(const float4*)(bo1 + 64 + tx * 4);
#pragma unroll
  for (int i = 0; i < 4; ++i) {
    size_t row = (size_t)(rbase + n0 + i);
    float q0[4] = {silu_f(acc[i][0] + bq0.x), silu_f(acc[i][1] + bq0.y),
                   silu_f(acc[i][2] + bq0.z), silu_f(acc[i][3] + bq0.w)};
    float q1[4] = {silu_f(acc[i][4] + bq1.x), silu_f(acc[i][5] + bq1.y),
                   silu_f(acc[i][6] + bq1.z), silu_f(acc[i][7] + bq1.w)};
    union { __bf16 bb[4]; uint2 u; } H, L;
#pragma unroll
    for (int e = 0; e < 4; ++e) {
      __bf16 hv = (__bf16)q0[e];
      H.bb[e] = hv;
      L.bb[e] = (__bf16)(q0[e] - (float)hv);
    }
    *(uint2*)(xh + row * 128 + tx * 4) = H.u;
    *(uint2*)(xl + row * 128 + tx * 4) = L.u;
#pragma unroll
    for (int e = 0; e < 4; ++e) {
      __bf16 hv = (__bf16)q1[e];
      H.bb[e] = hv;
      L.bb[e] = (__bf16)(q1[e] - (float)hv);
    }
    *(uint2*)(xh + row * 128 + 64 + tx * 4) = H.u;
    *(uint2*)(xl + row * 128 + 64 + tx * 4) = L.u;
  }
}

// ---------------- split-bf16 MFMA GEMM for head layers 2/3 ----------------
template<int MODE>
__global__ __launch_bounds__(256) void k_mgemm(
    const __bf16* Ah, const __bf16* Al,
    const __bf16* __restrict__ Bh, const __bf16* __restrict__ Bl,
    const float* __restrict__ bias,
    __bf16* Oh, __bf16* Ol, float* __restrict__ Of) {
  int rbase = blockIdx.y * 64;
  int cbase = blockIdx.x * 128;
  int t = threadIdx.x;
  int w = t >> 6;            // wave = M-tile
  int l = t & 63;
  int kg = l >> 4, ln = l & 15;

  __shared__ v8bf As[2][2][4][64];   // [buf][plane][mt][lane]  16 KB
  __shared__ v8bf Bs[2][2][8][64];   // [buf][plane][nt][lane]  32 KB

  size_t arow  = (size_t)(rbase + w * 16 + ln) * 128 + kg * 8;
  int nt0 = w, nt1 = w + 4;
  size_t brow0 = (size_t)(cbase + nt0 * 16 + ln) * 128 + kg * 8;
  size_t brow1 = (size_t)(cbase + nt1 * 16 + ln) * 128 + kg * 8;

  v8bf ra0, ra1, rb0, rb1, rb2, rb3;
  ra0 = *(const v8bf*)(Ah + arow);
  ra1 = *(const v8bf*)(Al + arow);
  rb0 = *(const v8bf*)(Bh + brow0);
  rb1 = *(const v8bf*)(Bh + brow1);
  rb2 = *(const v8bf*)(Bl + brow0);
  rb3 = *(const v8bf*)(Bl + brow1);
  As[0][0][w][l]   = ra0;
  As[0][1][w][l]   = ra1;
  Bs[0][0][nt0][l] = rb0;
  Bs[0][0][nt1][l] = rb1;
  Bs[0][1][nt0][l] = rb2;
  Bs[0][1][nt1][l] = rb3;
  __syncthreads();

  v4f acc[8];
  v4f z4 = {0.f, 0.f, 0.f, 0.f};
#pragma unroll
  for (int i = 0; i < 8; ++i) acc[i] = z4;

  for (int kb = 0; kb < 4; ++kb) {
    int cur = kb & 1;
    if (kb < 3) {
      int off = (kb + 1) * 32;
      ra0 = *(const v8bf*)(Ah + arow + off);
      ra1 = *(const v8bf*)(Al + arow + off);
      rb0 = *(const v8bf*)(Bh + brow0 + off);
      rb1 = *(const v8bf*)(Bh + brow1 + off);
      rb2 = *(const v8bf*)(Bl + brow0 + off);
      rb3 = *(const v8bf*)(Bl + brow1 + off);
    }
    v8bf ah  = As[cur][0][w][l];
    v8bf alo = As[cur][1][w][l];
#pragma unroll
    for (int nt = 0; nt < 8; ++nt) {
      v8bf bh = Bs[cur][0][nt][l];
      v8bf bl = Bs[cur][1][nt][l];
      acc[nt] = __builtin_amdgcn_mfma_f32_16x16x32_bf16(ah,  bh, acc[nt], 0, 0, 0);
      acc[nt] = __builtin_amdgcn_mfma_f32_16x16x32_bf16(alo, bh, acc[nt], 0, 0, 0);
      acc[nt] = __builtin_amdgcn_mfma_f32_16x16x32_bf16(ah,  bl, acc[nt], 0, 0, 0);
    }
    if (kb < 3) {
      int nxt = cur ^ 1;
      As[nxt][0][w][l]   = ra0;
      As[nxt][1][w][l]   = ra1;
      Bs[nxt][0][nt0][l] = rb0;
      Bs[nxt][0][nt1][l] = rb1;
      Bs[nxt][1][nt0][l] = rb2;
      Bs[nxt][1][nt1][l] = rb3;
    }
    __syncthreads();
  }

  // epilogue; D layout: col = lane&15 (within N-tile), row = (lane>>4)*4 + reg
  int r0 = rbase + w * 16 + kg * 4;
#pragma unroll
  for (int nt = 0; nt < 8; ++nt) {
    float bv = bias[cbase + nt * 16 + ln];
#pragma unroll
    for (int j = 0; j < 4; ++j) {
      float x = acc[nt][j] + bv;
      if (MODE == 0) {
        x = silu_f(x);
        __bf16 hv = (__bf16)x;
        size_t o = (size_t)(r0 + j) * 128 + nt * 16 + ln;
        Oh[o] = hv;
        Ol[o] = (__bf16)(x - (float)hv);
      } else {
        Of[(size_t)(r0 + j) * 256 + cbase + nt * 16 + ln] = x;
      }
    }
  }
}

extern "C" void kernel_launch(void* const* d_in, const int* in_sizes, int n_in,
                              void* d_out, int out_size, void* d_ws, size_t ws_size,
                              hipStream_t stream) {
  const float* h        = (const float*)d_in[0];
  const float* h_full   = (const float*)d_in[1];
  const int*   z        = (const int*)d_in[2];
  const float* e_feat   = (const float*)d_in[4];
  const int*   abs_idx  = (const int*)d_in[5];
  const int*   att_dst  = (const int*)d_in[6];
  const float* att_dist = (const float*)d_in[7];
  const float* att_vec  = (const float*)d_in[8];
  const float* w_zemb   = (const float*)d_in[9];
  const float* w1_rad   = (const float*)d_in[10];
  const float* b1_rad   = (const float*)d_in[11];
  const float* w2_rad   = (const float*)d_in[12];
  const float* b2_rad   = (const float*)d_in[13];
  const float* wg1      = (const float*)d_in[14];
  const float* bg1      = (const float*)d_in[15];
  const float* wg2      = (const float*)d_in[16];
  const float* bg2      = (const float*)d_in[17];
  const float* we1      = (const float*)d_in[18];
  const float* be1      = (const float*)d_in[19];
  const float* we2      = (const float*)d_in[20];
  const float* be2      = (const float*)d_in[21];
  const float* wo1      = (const float*)d_in[22];
  const float* bo1      = (const float*)d_in[23];
  const float* wo2      = (const float*)d_in[24];
  const float* bo2      = (const float*)d_in[25];
  const float* wo3      = (const float*)d_in[26];
  const float* bo3      = (const float*)d_in[27];
  float* out = (float*)d_out;

  // workspace: persistent small buffers, then big region where
  // phase-1 (ah/al/coef/acc/w2rt, 8.9 MB) and phase-2 (xh+xl, 16 MB) alias.
  float* meta_f  = (float*)d_ws;                 // MAXACT*4
  float* vabs    = meta_f + MAXACT * 4;          // 64*80
  float* sfull   = vabs + NB * OD_;              // 512*80
  float* habs_g  = sfull + NE_ * OD_;            // 64*128
  __bf16* w2t_h  = (__bf16*)(habs_g + NB * 128); // 128*128 bf16
  __bf16* w2t_l  = w2t_h + 128 * 128;
  __bf16* w3t_h  = w2t_l + 128 * 128;            // 256*128 bf16
  __bf16* w3t_l  = w3t_h + 256 * 128;
  int* widx   = (int*)(w3t_l + 256 * 128);       // 8192
  int* active = widx + FLAT;                     // 4096
  int* meta_b = active + MAXACT;                 // 4096
  int* count  = meta_b + MAXACT;                 // 1 (+pad to 16B)
  float* big  = (float*)(count + 15);            // aligned big region
  // phase 1:
  __bf16* ah_glob  = (__bf16*)big;               // MAXACT*128
  __bf16* al_glob  = ah_glob + MAXACT * 128;     // MAXACT*128
  float* coef_glob = (float*)(al_glob + MAXACT * 128);  // MAXACT*192
  float* acc_glob  = coef_glob + MAXACT * 192;   // MAXACT*96
  __bf16* w2rt_h   = (__bf16*)(acc_glob + MAXACT * 96); // 4608*128
  __bf16* w2rt_l   = w2rt_h + 4608 * 128;
  // phase 2 (aliases phase 1, all phase-1 consumers done before k_hg1):
  __bf16* xh       = (__bf16*)big;               // 32768*128
  __bf16* xl       = xh + (size_t)32768 * 128;   // 32768*128

  k_init<<<1536, 256, 0, stream>>>(acc_glob, vabs, widx, count);
  k_wprep<<<384, 128, 0, stream>>>(wo2, wo3, w2t_h, w2t_l, w3t_h, w3t_l);
  k_wprep2<<<144, 256, 0, stream>>>(w2_rad, w2rt_h, w2rt_l);
  k_scatter<<<16, 256, 0, stream>>>(att_dst, widx);
  k_build<<<32, 256, 0, stream>>>(widx, active, count);
  k_gabs<<<NB, 128, 0, stream>>>(abs_idx, h, wg1, habs_g);
  k_node<<<MAXACT, 128, 0, stream>>>(count, active, widx, att_dist, att_vec, z, w_zemb,
                                     abs_idx, w1_rad, b1_rad, h, habs_g, wg1, bg1, wg2, bg2,
                                     h_full, ah_glob, al_glob, coef_glob, meta_f, meta_b);
  k_mrgemm<<<dim3(36, 32), 256, 0, stream>>>(count, ah_glob, al_glob, w2rt_h, w2rt_l,
                                             b2_rad, coef_glob, acc_glob);
  k_combine<<<1536, 256, 0, stream>>>(count, acc_glob, meta_f, meta_b, vabs);
  k_scales<<<512, 128, 0, stream>>>(e_feat, we1, be1, we2, be2, sfull);
  k_hg1<<<512, 256, 0, stream>>>(vabs, sfull, wo1, bo1, xh, xl);
  k_mgemm<0><<<dim3(1, 512), 256, 0, stream>>>(xh, xl, w2t_h, w2t_l, bo2,
                                               xh, xl, nullptr);
  k_mgemm<1><<<dim3(2, 512), 256, 0, stream>>>(xh, xl, w3t_h, w3t_l, bo3,
                                               nullptr, nullptr, out);
}

// Round 3
// 248.394 us; speedup vs baseline: 1.2547x; 1.0353x over previous
//
#include <hip/hip_runtime.h>
#include <math.h>

#define FLAT   8192
#define NB     64
#define OD_    80
#define NE_    512
#define EATT_  4096
#define MAXACT 4096
// part: 1088 floats/node of contraction partials, written by k_mrgemm with
// plain stores (no atomics), reduced by k_combine:
//   [0..767]   24 cc-slices x 32 out_s slots
//   [768..895]  8 cc-slices x 16 q slots
//   [896..1087] 4 cc-slices x 48 D-term slots (comp*16+o)
#define PARTW 1088

typedef __bf16 v8bf __attribute__((ext_vector_type(8)));
typedef float  v4f  __attribute__((ext_vector_type(4)));

__device__ __forceinline__ float silu_f(float x) { return x / (1.f + __expf(-x)); }
__device__ __forceinline__ float sigm_f(float x) { return 1.f / (1.f + __expf(-x)); }

// ---------------- init: zero vabs, widx=-1, count=0 ----------------
__global__ void k_init(float* vabs, int* widx, int* count) {
  int t = blockIdx.x * 256 + threadIdx.x;
  if (t < FLAT) widx[t] = -1;
  if (t < NB * OD_) vabs[t] = 0.f;
  if (t == 0) *count = 0;
}

// ---------------- scatter: last-write-wins == max edge index ----------------
__global__ void k_scatter(const int* __restrict__ att_dst, int* widx) {
  int i = blockIdx.x * 256 + threadIdx.x;
  if (i < EATT_) atomicMax(&widx[att_dst[i]], i);
}

// ---------------- compact active-node list ----------------
__global__ void k_build(const int* __restrict__ widx, int* active, int* count) {
  int j = blockIdx.x * 256 + threadIdx.x;
  if (j < FLAT && widx[j] >= 0) {
    int p = atomicAdd(count, 1);
    active[p] = j;
  }
}

// ---------------- per-batch absorber row of gate layer 1: h_abs @ wg1 ----------------
__global__ void k_gabs(const int* __restrict__ abs_idx, const float* __restrict__ h,
                       const float* __restrict__ wg1, float* habs_g) {
  int b = blockIdx.x;   // 64
  int t = threadIdx.x;  // 128
  __shared__ float hs[128];
  int nabs = abs_idx[b];
  hs[t] = h[(size_t)(b * 128 + nabs) * 128 + t];
  __syncthreads();
  float g = 0.f;
  for (int c = 0; c < 128; ++c) g = fmaf(hs[c], wg1[c * 128 + t], g);
  habs_g[b * 128 + t] = g;
}

// ---------------- transpose+split head weights to bf16 hi/lo, [n][k] ----------------
__global__ void k_wprep(const float* __restrict__ wo2, const float* __restrict__ wo3,
                        __bf16* w2h, __bf16* w2l, __bf16* w3h, __bf16* w3l) {
  int b = blockIdx.x;   // 0..383
  int t = threadIdx.x;  // 128 = k index
  if (b < 128) {
    float v = wo2[t * 128 + b];
    __bf16 h = (__bf16)v;
    w2h[b * 128 + t] = h;
    w2l[b * 128 + t] = (__bf16)(v - (float)h);
  } else {
    int n = b - 128;
    float v = wo3[t * 256 + n];
    __bf16 h = (__bf16)v;
    w3h[n * 128 + t] = h;
    w3l[n * 128 + t] = (__bf16)(v - (float)h);
  }
}

// ---------------- transpose+split radial weights: w2_rad [128k][4608n] -> [n][k] hi/lo ----
__global__ void k_wprep2(const float* __restrict__ w2, __bf16* wh, __bf16* wl) {
  int n = blockIdx.x * 32 + (threadIdx.x >> 3);   // 144 blocks -> n in 0..4607
  int k0 = (threadIdx.x & 7) * 16;
  union { __bf16 b[16]; uint4 u[2]; } H, L;
#pragma unroll
  for (int kk = 0; kk < 16; ++kk) {
    float v = w2[(size_t)(k0 + kk) * 4608 + n];
    __bf16 hv = (__bf16)v;
    H.b[kk] = hv;
    L.b[kk] = (__bf16)(v - (float)hv);
  }
  *(uint4*)(wh + (size_t)n * 128 + k0)     = H.u[0];
  *(uint4*)(wh + (size_t)n * 128 + k0 + 8) = H.u[1];
  *(uint4*)(wl + (size_t)n * 128 + k0)     = L.u[0];
  *(uint4*)(wl + (size_t)n * 128 + k0 + 8) = L.u[1];
}

// ---------------- per active node: rbf, hidden a(128) as bf16 hi/lo, gate, env, coefs ----
__global__ void k_node(const int* __restrict__ count, const int* __restrict__ active,
                       const int* __restrict__ widx,
                       const float* __restrict__ att_dist, const float* __restrict__ att_vec,
                       const int* __restrict__ z, const float* __restrict__ w_zemb,
                       const int* __restrict__ abs_idx,
                       const float* __restrict__ w1_rad, const float* __restrict__ b1_rad,
                       const float* __restrict__ h, const float* __restrict__ habs_g,
                       const float* __restrict__ wg1, const float* __restrict__ bg1,
                       const float* __restrict__ wg2, const float* __restrict__ bg2,
                       const float* __restrict__ h_full,
                       __bf16* ah_glob, __bf16* al_glob,
                       float* coef_glob, float* meta_f, int* meta_b) {
  int pos = blockIdx.x;
  if (pos >= *count) return;
  int t = threadIdx.x;  // 128 threads
  __shared__ float win[49];
  __shared__ float yv_s[3];
  __shared__ float red[128];
  __shared__ float sh_d;

  int j = active[pos];
  int b = j >> 7;
  int n = j & 127;
  int e = widx[j];

  if (t == 0) {
    float d = att_dist[e];
    sh_d = d;
    float eps = fmaxf(d, 1e-8f);
    const float s3 = 1.7320508075688772f;
    yv_s[0] = s3 * att_vec[e * 3 + 0] / eps;
    yv_s[1] = s3 * att_vec[e * 3 + 1] / eps;
    yv_s[2] = s3 * att_vec[e * 3 + 2] / eps;
  }
  int nabs = abs_idx[b];
  float isab = (n == nabs) ? 1.f : 0.f;
  if (t < 32) win[t] = w_zemb[z[j] * 32 + t];
  if (t == 32) win[32] = isab;
  if (t >= 33 && t < 49) {
    int k = t - 33;
    float d = att_dist[e];
    float x = (d - (float)k * (1.f / 3.f)) * 3.f;  // width = CUTOFF/(RBF-1) = 1/3
    win[t] = __expf(-0.5f * x * x);
  }
  __syncthreads();

  // hidden a = silu(win @ w1_rad + b1_rad)   (49 -> 128), stored as bf16 hi/lo
  {
    float s = b1_rad[t];
    for (int k = 0; k < 49; ++k) s = fmaf(win[k], w1_rad[k * 128 + t], s);
    float av = silu_f(s);
    __bf16 hv = (__bf16)av;
    ah_glob[pos * 128 + t] = hv;
    al_glob[pos * 128 + t] = (__bf16)(av - (float)hv);
  }

  // gate MLP hidden (273 -> 128); h_abs part precomputed per-batch (k_gabs)
  {
    float g = bg1[t] + habs_g[b * 128 + t];
    const float* hn = h + (size_t)j * 128;
    for (int c = 0; c < 128; ++c) g = fmaf(hn[c], wg1[(128 + c) * 128 + t], g);
    for (int k = 0; k < 16; ++k)  g = fmaf(win[33 + k], wg1[(256 + k) * 128 + t], g);
    g = fmaf(isab, wg1[272 * 128 + t], g);
    red[t] = silu_f(g) * wg2[t];
  }
  __syncthreads();

  // per-node contraction coefficients: [s1(64), p*inv_s3(32), v1(96)]
  const float* hf = h_full + (size_t)j * 160;
  if (t < 64) coef_glob[pos * 192 + t] = hf[t];
  if (t >= 64 && t < 96) {
    int i = t - 64;
    float pv = hf[64 + i * 3 + 0] * yv_s[0] + hf[64 + i * 3 + 1] * yv_s[1] +
               hf[64 + i * 3 + 2] * yv_s[2];
    coef_glob[pos * 192 + t] = pv * 0.5773502691896258f;
  }
  if (t < 96) coef_glob[pos * 192 + 96 + t] = hf[64 + t];

  if (t == 0) {
    float tot = 0.f;
    for (int k = 0; k < 128; ++k) tot += red[k];
    tot += bg2[0];
    float gate = sigm_f(tot);
    float d = sh_d;
    float env = (d < 5.f) ? 0.5f * (__cosf(3.14159265358979323846f * d * 0.2f) + 1.f) : 0.f;
    meta_f[pos * 4 + 0] = yv_s[0];
    meta_f[pos * 4 + 1] = yv_s[1];
    meta_f[pos * 4 + 2] = yv_s[2];
    meta_f[pos * 4 + 3] = gate * env;
    meta_b[pos] = b;
  }
}

// ---------------- split-bf16 MFMA radial GEMM + fused contraction ----------------
// tpw = a[node][128k] @ w2rt[4608n][128k]^T + b2, contracted on the fly.
// Partials go to part[node][1088] via PLAIN COALESCED STORES (each (node,
// slot, cc-slice) is owned by exactly one thread) — no atomics; k_combine
// reduces the 24/8/4 slices per slot.
__global__ __launch_bounds__(256) void k_mrgemm(
    const int* __restrict__ count,
    const __bf16* Ah, const __bf16* Al,
    const __bf16* __restrict__ Bh, const __bf16* __restrict__ Bl,
    const float* __restrict__ b2, const float* __restrict__ coef_glob,
    float* __restrict__ part) {
  int cc = blockIdx.x;            // 0..35
  int nbase = blockIdx.y * 128;   // 32 y-blocks
  int cnt = *count;
  if (nbase >= cnt) return;
  int t = threadIdx.x;
  int w = t >> 6, l = t & 63;
  int kg = l >> 4, ln = l & 15;
  int cbase = cc * 128;

  __shared__ v8bf Bs[2][2][8][64];   // [buf][plane][nt][lane] 32 KB

  size_t brow0 = (size_t)(cbase + w * 16 + ln) * 128 + kg * 8;
  size_t brow1 = (size_t)(cbase + (w + 4) * 16 + ln) * 128 + kg * 8;
  size_t arow0 = (size_t)(nbase + (2 * w) * 16 + ln) * 128 + kg * 8;
  size_t arow1 = (size_t)(nbase + (2 * w + 1) * 16 + ln) * 128 + kg * 8;

  v8bf rb0 = *(const v8bf*)(Bh + brow0);
  v8bf rb1 = *(const v8bf*)(Bh + brow1);
  v8bf rb2 = *(const v8bf*)(Bl + brow0);
  v8bf rb3 = *(const v8bf*)(Bl + brow1);
  v8bf ah0 = *(const v8bf*)(Ah + arow0);
  v8bf al0 = *(const v8bf*)(Al + arow0);
  v8bf ah1 = *(const v8bf*)(Ah + arow1);
  v8bf al1 = *(const v8bf*)(Al + arow1);
  Bs[0][0][w][l]     = rb0;
  Bs[0][0][w + 4][l] = rb1;
  Bs[0][1][w][l]     = rb2;
  Bs[0][1][w + 4][l] = rb3;
  __syncthreads();

  v4f acc[2][8];
  v4f z4 = {0.f, 0.f, 0.f, 0.f};
#pragma unroll
  for (int i = 0; i < 2; ++i)
#pragma unroll
    for (int j = 0; j < 8; ++j) acc[i][j] = z4;

  for (int kb = 0; kb < 4; ++kb) {
    int cur = kb & 1;
    v8bf nb0, nb1, nb2, nb3, nh0, nl0, nh1, nl1;
    if (kb < 3) {
      int off = (kb + 1) * 32;
      nb0 = *(const v8bf*)(Bh + brow0 + off);
      nb1 = *(const v8bf*)(Bh + brow1 + off);
      nb2 = *(const v8bf*)(Bl + brow0 + off);
      nb3 = *(const v8bf*)(Bl + brow1 + off);
      nh0 = *(const v8bf*)(Ah + arow0 + off);
      nl0 = *(const v8bf*)(Al + arow0 + off);
      nh1 = *(const v8bf*)(Ah + arow1 + off);
      nl1 = *(const v8bf*)(Al + arow1 + off);
    }
#pragma unroll
    for (int nt = 0; nt < 8; ++nt) {
      v8bf bh = Bs[cur][0][nt][l];
      v8bf bl = Bs[cur][1][nt][l];
      acc[0][nt] = __builtin_amdgcn_mfma_f32_16x16x32_bf16(ah0, bh, acc[0][nt], 0, 0, 0);
      acc[0][nt] = __builtin_amdgcn_mfma_f32_16x16x32_bf16(al0, bh, acc[0][nt], 0, 0, 0);
      acc[0][nt] = __builtin_amdgcn_mfma_f32_16x16x32_bf16(ah0, bl, acc[0][nt], 0, 0, 0);
      acc[1][nt] = __builtin_amdgcn_mfma_f32_16x16x32_bf16(ah1, bh, acc[1][nt], 0, 0, 0);
      acc[1][nt] = __builtin_amdgcn_mfma_f32_16x16x32_bf16(al1, bh, acc[1][nt], 0, 0, 0);
      acc[1][nt] = __builtin_amdgcn_mfma_f32_16x16x32_bf16(ah1, bl, acc[1][nt], 0, 0, 0);
    }
    if (kb < 3) {
      int nxt = cur ^ 1;
      Bs[nxt][0][w][l]     = nb0;
      Bs[nxt][0][w + 4][l] = nb1;
      Bs[nxt][1][w][l]     = nb2;
      Bs[nxt][1][w + 4][l] = nb3;
      ah0 = nh0; al0 = nl0; ah1 = nh1; al1 = nl1;
    }
    __syncthreads();
  }

  // bias (tpw-layer bias, added before contraction — linear, so per-element)
  float b2v[8];
#pragma unroll
  for (int nt = 0; nt < 8; ++nt) b2v[nt] = b2[cbase + nt * 16 + ln];

#pragma unroll
  for (int mi = 0; mi < 2; ++mi) {
    int nodeb = nbase + (2 * w + mi) * 16 + kg * 4;
#pragma unroll
    for (int j = 0; j < 4; ++j) {
      int nd = nodeb + j;
      if (nd >= cnt) continue;
      const float* cf = coef_glob + (size_t)nd * 192;
      if (cc < 24) {
        float s0 = 0.f, s1 = 0.f;
#pragma unroll
        for (int m = 0; m < 4; ++m) {
          float c = cf[cc * 4 + m];
          s0 = fmaf(acc[mi][2 * m][j] + b2v[2 * m], c, s0);
          s1 = fmaf(acc[mi][2 * m + 1][j] + b2v[2 * m + 1], c, s1);
        }
        float* pp = part + (size_t)nd * PARTW + cc * 32 + ln;
        pp[0]  = s0;
        pp[16] = s1;
      } else if (cc < 32) {
        float s = 0.f;
#pragma unroll
        for (int nt = 0; nt < 8; ++nt)
          s = fmaf(acc[mi][nt][j] + b2v[nt], cf[(cc - 24) * 8 + nt], s);
        part[(size_t)nd * PARTW + 768 + (cc - 24) * 16 + ln] = s;
      } else {
        float s0 = 0.f, s1 = 0.f, s2 = 0.f;
#pragma unroll
        for (int nt = 0; nt < 8; ++nt) {
          float x = acc[mi][nt][j] + b2v[nt];
          const float* c3 = cf + 96 + ((cc - 32) * 8 + nt) * 3;
          s0 = fmaf(x, c3[0], s0);
          s1 = fmaf(x, c3[1], s1);
          s2 = fmaf(x, c3[2], s2);
        }
        float* pp = part + (size_t)nd * PARTW + 896 + (cc - 32) * 48 + ln;
        pp[0]  = s0;
        pp[16] = s1;
        pp[32] = s2;
      }
    }
  }
}

// ---------------- reduce part slices -> v_abs[b][80] ----------------
// 128 threads per node (2 nodes/block); slot-thread sums its 24/8/4 slices.
__global__ void k_combine(const int* __restrict__ count, const float* __restrict__ part,
                          const float* __restrict__ meta_f, const int* __restrict__ meta_b,
                          float* vabs) {
  int t = threadIdx.x;
  int pos = blockIdx.x * 2 + (t >> 7);
  int slot = t & 127;
  if (pos >= *count || slot >= 96) return;
  const float* pp = part + (size_t)pos * PARTW;
  float s = 0.f;
  if (slot < 32) {
#pragma unroll
    for (int c = 0; c < 24; ++c) s += pp[c * 32 + slot];
  } else if (slot < 48) {
#pragma unroll
    for (int c = 0; c < 8; ++c) s += pp[768 + c * 16 + (slot - 32)];
  } else {
#pragma unroll
    for (int c = 0; c < 4; ++c) s += pp[896 + c * 48 + (slot - 48)];
  }
  float sc = meta_f[pos * 4 + 3] * 0.10206207261596577f;  // gate*env / sqrt(96)
  float* vb = vabs + meta_b[pos] * 80;
  if (slot < 32) {
    unsafeAtomicAdd(&vb[slot], s * sc);
  } else if (slot < 48) {
    int o = slot - 32;
    float q = s * sc;
    unsafeAtomicAdd(&vb[32 + o * 3 + 0], q * meta_f[pos * 4 + 0]);
    unsafeAtomicAdd(&vb[32 + o * 3 + 1], q * meta_f[pos * 4 + 1]);
    unsafeAtomicAdd(&vb[32 + o * 3 + 2], q * meta_f[pos * 4 + 2]);
  } else {
    int s2 = slot - 48;          // comp*16 + o
    int comp = s2 >> 4, o = s2 & 15;
    unsafeAtomicAdd(&vb[32 + o * 3 + comp], s * sc);
  }
}

// ---------------- edge-feature scales -> scale_full[512][80] ----------------
__global__ void k_scales(const float* __restrict__ e_feat,
                         const float* __restrict__ we1, const float* __restrict__ be1,
                         const float* __restrict__ we2, const float* __restrict__ be2,
                         float* sfull) {
  int row = blockIdx.x;  // 512
  int t = threadIdx.x;   // 128
  __shared__ float hid[128];
  const float* ef = e_feat + row * 16;
  float s = be1[t];
  for (int k = 0; k < 16; ++k) s = fmaf(ef[k], we1[k * 128 + t], s);
  hid[t] = silu_f(s);
  __syncthreads();
  if (t < 48) {
    float o = be2[t];
    for (int k = 0; k < 128; ++k) o = fmaf(hid[k], we2[k * 48 + t], o);
    if (t < 32) sfull[row * 80 + t] = o;
    else {
      int oo = t - 32;
      sfull[row * 80 + 32 + oo * 3 + 0] = o;
      sfull[row * 80 + 32 + oo * 3 + 1] = o;
      sfull[row * 80 + 32 + oo * 3 + 2] = o;
    }
  }
}

// ---------------- head G1: build inv + (32768x48)@wo1 + silu -> xh/xl (bf16 hi/lo) ----------------
__global__ __launch_bounds__(256) void k_hg1(const float* __restrict__ vabs,
                                             const float* __restrict__ sfull,
                                             const float* __restrict__ wo1,
                                             const float* __restrict__ bo1,
                                             __bf16* __restrict__ xh,
                                             __bf16* __restrict__ xl) {
  int rbase = blockIdx.x * 64;   // 512 blocks
  int b = rbase >> 9;
  int e0 = rbase & 511;
  int t = threadIdx.x;
  int tx = t & 15, ty = t >> 4;
  int n0 = ty * 4;

  __shared__ float w_s[48 * 128];   // [k][col], 24 KB
  __shared__ float invt[48][64];    // [k][row], 12 KB
  __shared__ float va[80];

  if (t < 80) va[t] = vabs[b * 80 + t];
  {
    const float4* wg = (const float4*)wo1;
    float4* ws4 = (float4*)w_s;
#pragma unroll
    for (int it = 0; it < 6; ++it) ws4[t + it * 256] = wg[t + it * 256];
  }
  __syncthreads();

  // inv transposed [c][row]: 48*64 elems, 12 per thread
  for (int idx = t; idx < 48 * 64; idx += 256) {
    int cd = idx >> 6, r = idx & 63;
    const float* sf = sfull + (size_t)(e0 + r) * 80;
    float v;
    if (cd < 32) v = va[cd] * sf[cd];
    else {
      int base = 32 + (cd - 32) * 3;
      float m0 = va[base + 0] * sf[base + 0];
      float m1 = va[base + 1] * sf[base + 1];
      float m2 = va[base + 2] * sf[base + 2];
      v = sqrtf(m0 * m0 + m1 * m1 + m2 * m2 + 1e-12f);
    }
    invt[cd][r] = v;
  }
  __syncthreads();

  float acc[4][8];
#pragma unroll
  for (int i = 0; i < 4; ++i)
#pragma unroll
    for (int j = 0; j < 8; ++j) acc[i][j] = 0.f;

  for (int k = 0; k < 48; ++k) {
    float4 av  = *(const float4*)&invt[k][n0];
    float4 w0  = *(const float4*)&w_s[k * 128 + tx * 4];
    float4 w1v = *(const float4*)&w_s[k * 128 + 64 + tx * 4];
#pragma unroll
    for (int i = 0; i < 4; ++i) {
      float a = (i == 0) ? av.x : (i == 1) ? av.y : (i == 2) ? av.z : av.w;
      acc[i][0] = fmaf(a, w0.x,  acc[i][0]);
      acc[i][1] = fmaf(a, w0.y,  acc[i][1]);
      acc[i][2] = fmaf(a, w0.z,  acc[i][2]);
      acc[i][3] = fmaf(a, w0.w,  acc[i][3]);
      acc[i][4] = fmaf(a, w1v.x, acc[i][4]);
      acc[i][5] = fmaf(a, w1v.y, acc[i][5]);
      acc[i][6] = fmaf(a, w1v.z, acc[i][6]);
      acc[i][7] = fmaf(a, w1v.w, acc[i][7]);
    }
  }

  float4 bq0 = *(const float4*)(bo1 + tx * 4);
  float4 bq1 = *(const float4*)(bo1 + 64 + tx * 4);
#pragma unroll
  for (int i = 0; i < 4; ++i) {
    size_t row = (size_t)(rbase + n0 + i);
    float q0[4] = {silu_f(acc[i][0] + bq0.x), silu_f(acc[i][1] + bq0.y),
                   silu_f(acc[i][2] + bq0.z), silu_f(acc[i][3] + bq0.w)};
    float q1[4] = {silu_f(acc[i][4] + bq1.x), silu_f(acc[i][5] + bq1.y),
                   silu_f(acc[i][6] + bq1.z), silu_f(acc[i][7] + bq1.w)};
    union { __bf16 bb[4]; uint2 u; } H, L;
#pragma unroll
    for (int e = 0; e < 4; ++e) {
      __bf16 hv = (__bf16)q0[e];
      H.bb[e] = hv;
      L.bb[e] = (__bf16)(q0[e] - (float)hv);
    }
    *(uint2*)(xh + row * 128 + tx * 4) = H.u;
    *(uint2*)(xl + row * 128 + tx * 4) = L.u;
#pragma unroll
    for (int e = 0; e < 4; ++e) {
      __bf16 hv = (__bf16)q1[e];
      H.bb[e] = hv;
      L.bb[e] = (__bf16)(q1[e] - (float)hv);
    }
    *(uint2*)(xh + row * 128 + 64 + tx * 4) = H.u;
    *(uint2*)(xl + row * 128 + 64 + tx * 4) = L.u;
  }
}

// ---------------- split-bf16 MFMA GEMM for head layers 2/3 ----------------
template<int MODE>
__global__ __launch_bounds__(256) void k_mgemm(
    const __bf16* Ah, const __bf16* Al,
    const __bf16* __restrict__ Bh, const __bf16* __restrict__ Bl,
    const float* __restrict__ bias,
    __bf16* Oh, __bf16* Ol, float* __restrict__ Of) {
  int rbase = blockIdx.y * 64;
  int cbase = blockIdx.x * 128;
  int t = threadIdx.x;
  int w = t >> 6;            // wave = M-tile
  int l = t & 63;
  int kg = l >> 4, ln = l & 15;

  __shared__ v8bf As[2][2][4][64];   // [buf][plane][mt][lane]  16 KB
  __shared__ v8bf Bs[2][2][8][64];   // [buf][plane][nt][lane]  32 KB

  size_t arow  = (size_t)(rbase + w * 16 + ln) * 128 + kg * 8;
  int nt0 = w, nt1 = w + 4;
  size_t brow0 = (size_t)(cbase + nt0 * 16 + ln) * 128 + kg * 8;
  size_t brow1 = (size_t)(cbase + nt1 * 16 + ln) * 128 + kg * 8;

  v8bf ra0, ra1, rb0, rb1, rb2, rb3;
  ra0 = *(const v8bf*)(Ah + arow);
  ra1 = *(const v8bf*)(Al + arow);
  rb0 = *(const v8bf*)(Bh + brow0);
  rb1 = *(const v8bf*)(Bh + brow1);
  rb2 = *(const v8bf*)(Bl + brow0);
  rb3 = *(const v8bf*)(Bl + brow1);
  As[0][0][w][l]   = ra0;
  As[0][1][w][l]   = ra1;
  Bs[0][0][nt0][l] = rb0;
  Bs[0][0][nt1][l] = rb1;
  Bs[0][1][nt0][l] = rb2;
  Bs[0][1][nt1][l] = rb3;
  __syncthreads();

  v4f acc[8];
  v4f z4 = {0.f, 0.f, 0.f, 0.f};
#pragma unroll
  for (int i = 0; i < 8; ++i) acc[i] = z4;

  for (int kb = 0; kb < 4; ++kb) {
    int cur = kb & 1;
    if (kb < 3) {
      int off = (kb + 1) * 32;
      ra0 = *(const v8bf*)(Ah + arow + off);
      ra1 = *(const v8bf*)(Al + arow + off);
      rb0 = *(const v8bf*)(Bh + brow0 + off);
      rb1 = *(const v8bf*)(Bh + brow1 + off);
      rb2 = *(const v8bf*)(Bl + brow0 + off);
      rb3 = *(const v8bf*)(Bl + brow1 + off);
    }
    v8bf ah  = As[cur][0][w][l];
    v8bf alo = As[cur][1][w][l];
#pragma unroll
    for (int nt = 0; nt < 8; ++nt) {
      v8bf bh = Bs[cur][0][nt][l];
      v8bf bl = Bs[cur][1][nt][l];
      acc[nt] = __builtin_amdgcn_mfma_f32_16x16x32_bf16(ah,  bh, acc[nt], 0, 0, 0);
      acc[nt] = __builtin_amdgcn_mfma_f32_16x16x32_bf16(alo, bh, acc[nt], 0, 0, 0);
      acc[nt] = __builtin_amdgcn_mfma_f32_16x16x32_bf16(ah,  bl, acc[nt], 0, 0, 0);
    }
    if (kb < 3) {
      int nxt = cur ^ 1;
      As[nxt][0][w][l]   = ra0;
      As[nxt][1][w][l]   = ra1;
      Bs[nxt][0][nt0][l] = rb0;
      Bs[nxt][0][nt1][l] = rb1;
      Bs[nxt][1][nt0][l] = rb2;
      Bs[nxt][1][nt1][l] = rb3;
    }
    __syncthreads();
  }

  // epilogue; D layout: col = lane&15 (within N-tile), row = (lane>>4)*4 + reg
  int r0 = rbase + w * 16 + kg * 4;
#pragma unroll
  for (int nt = 0; nt < 8; ++nt) {
    float bv = bias[cbase + nt * 16 + ln];
#pragma unroll
    for (int j = 0; j < 4; ++j) {
      float x = acc[nt][j] + bv;
      if (MODE == 0) {
        x = silu_f(x);
        __bf16 hv = (__bf16)x;
        size_t o = (size_t)(r0 + j) * 128 + nt * 16 + ln;
        Oh[o] = hv;
        Ol[o] = (__bf16)(x - (float)hv);
      } else {
        Of[(size_t)(r0 + j) * 256 + cbase + nt * 16 + ln] = x;
      }
    }
  }
}

extern "C" void kernel_launch(void* const* d_in, const int* in_sizes, int n_in,
                              void* d_out, int out_size, void* d_ws, size_t ws_size,
                              hipStream_t stream) {
  const float* h        = (const float*)d_in[0];
  const float* h_full   = (const float*)d_in[1];
  const int*   z        = (const int*)d_in[2];
  const float* e_feat   = (const float*)d_in[4];
  const int*   abs_idx  = (const int*)d_in[5];
  const int*   att_dst  = (const int*)d_in[6];
  const float* att_dist = (const float*)d_in[7];
  const float* att_vec  = (const float*)d_in[8];
  const float* w_zemb   = (const float*)d_in[9];
  const float* w1_rad   = (const float*)d_in[10];
  const float* b1_rad   = (const float*)d_in[11];
  const float* w2_rad   = (const float*)d_in[12];
  const float* b2_rad   = (const float*)d_in[13];
  const float* wg1      = (const float*)d_in[14];
  const float* bg1      = (const float*)d_in[15];
  const float* wg2      = (const float*)d_in[16];
  const float* bg2      = (const float*)d_in[17];
  const float* we1      = (const float*)d_in[18];
  const float* be1      = (const float*)d_in[19];
  const float* we2      = (const float*)d_in[20];
  const float* be2      = (const float*)d_in[21];
  const float* wo1      = (const float*)d_in[22];
  const float* bo1      = (const float*)d_in[23];
  const float* wo2      = (const float*)d_in[24];
  const float* bo2      = (const float*)d_in[25];
  const float* wo3      = (const float*)d_in[26];
  const float* bo3      = (const float*)d_in[27];
  float* out = (float*)d_out;

  // workspace: persistent small buffers, then big region where
  // phase-1 (ah/al/coef/w2rt/part, ~25 MB) and phase-2 (xh+xl, 16 MB) alias.
  float* meta_f  = (float*)d_ws;                 // MAXACT*4
  float* vabs    = meta_f + MAXACT * 4;          // 64*80
  float* sfull   = vabs + NB * OD_;              // 512*80
  float* habs_g  = sfull + NE_ * OD_;            // 64*128
  __bf16* w2t_h  = (__bf16*)(habs_g + NB * 128); // 128*128 bf16
  __bf16* w2t_l  = w2t_h + 128 * 128;
  __bf16* w3t_h  = w2t_l + 128 * 128;            // 256*128 bf16
  __bf16* w3t_l  = w3t_h + 256 * 128;
  int* widx   = (int*)(w3t_l + 256 * 128);       // 8192
  int* active = widx + FLAT;                     // 4096
  int* meta_b = active + MAXACT;                 // 4096
  int* count  = meta_b + MAXACT;                 // 1 (+pad to 16B)
  float* big  = (float*)(count + 15);            // aligned big region
  // phase 1:
  __bf16* ah_glob  = (__bf16*)big;               // MAXACT*128
  __bf16* al_glob  = ah_glob + MAXACT * 128;     // MAXACT*128
  float* coef_glob = (float*)(al_glob + MAXACT * 128);  // MAXACT*192
  __bf16* w2rt_h   = (__bf16*)(coef_glob + MAXACT * 192); // 4608*128
  __bf16* w2rt_l   = w2rt_h + 4608 * 128;
  float* part      = (float*)(w2rt_l + 4608 * 128);     // MAXACT*1088 (17.8 MB)
  // phase 2 (aliases phase 1, all phase-1 consumers done before k_hg1):
  __bf16* xh       = (__bf16*)big;               // 32768*128
  __bf16* xl       = xh + (size_t)32768 * 128;   // 32768*128

  k_init<<<32, 256, 0, stream>>>(vabs, widx, count);
  k_wprep<<<384, 128, 0, stream>>>(wo2, wo3, w2t_h, w2t_l, w3t_h, w3t_l);
  k_wprep2<<<144, 256, 0, stream>>>(w2_rad, w2rt_h, w2rt_l);
  k_scatter<<<16, 256, 0, stream>>>(att_dst, widx);
  k_build<<<32, 256, 0, stream>>>(widx, active, count);
  k_gabs<<<NB, 128, 0, stream>>>(abs_idx, h, wg1, habs_g);
  k_node<<<MAXACT, 128, 0, stream>>>(count, active, widx, att_dist, att_vec, z, w_zemb,
                                     abs_idx, w1_rad, b1_rad, h, habs_g, wg1, bg1, wg2, bg2,
                                     h_full, ah_glob, al_glob, coef_glob, meta_f, meta_b);
  k_mrgemm<<<dim3(36, 32), 256, 0, stream>>>(count, ah_glob, al_glob, w2rt_h, w2rt_l,
                                             b2_rad, coef_glob, part);
  k_combine<<<MAXACT / 2, 256, 0, stream>>>(count, part, meta_f, meta_b, vabs);
  k_scales<<<512, 128, 0, stream>>>(e_feat, we1, be1, we2, be2, sfull);
  k_hg1<<<512, 256, 0, stream>>>(vabs, sfull, wo1, bo1, xh, xl);
  k_mgemm<0><<<dim3(1, 512), 256, 0, stream>>>(xh, xl, w2t_h, w2t_l, bo2,
                                               xh, xl, nullptr);
  k_mgemm<1><<<dim3(2, 512), 256, 0, stream>>>(xh, xl, w3t_h, w3t_l, bo3,
                                               nullptr, nullptr, out);
}

// Round 4
// 234.497 us; speedup vs baseline: 1.3290x; 1.0593x over previous
//
#include <hip/hip_runtime.h>
#include <math.h>

#define FLAT   8192
#define NB     64
#define OD_    80
#define NE_    512
#define EATT_  4096
#define MAXACT 4096
// part: 1088 floats/node of contraction partials, written by k_mrgemm with
// plain stores (no atomics), reduced by k_post(combine):
//   [0..767]   24 cc-slices x 32 out_s slots
//   [768..895]  8 cc-slices x 16 q slots
//   [896..1087] 4 cc-slices x 48 D-term slots (comp*16+o)
#define PARTW 1088

typedef __bf16 v8bf __attribute__((ext_vector_type(8)));
typedef float  v4f  __attribute__((ext_vector_type(4)));

__device__ __forceinline__ float silu_f(float x) { return x / (1.f + __expf(-x)); }
__device__ __forceinline__ float sigm_f(float x) { return 1.f / (1.f + __expf(-x)); }

// ================= k_prep: init + gabs + coalesced weight transposes =================
// blocks 0..35  : w2_rad [128k][4608n] -> w2rt hi/lo [n][k], 128-col tiles
// block  36     : wo2 [128k][128n] -> w2t hi/lo [n][k]
// blocks 37..38 : wo3 [128k][256n] -> w3t hi/lo [n][k], two 128-col tiles
// blocks 39..70 : gabs (2 batches per block)
// blocks 71..102: init (widx=-1, vabs=0, count=0)
__device__ __forceinline__ void transpose_split(const float* __restrict__ src, int ld,
                                                int nbase, __bf16* wh, __bf16* wl,
                                                float (*lds)[129]) {
  int t = threadIdx.x;  // 256
  // load 128 rows x 128 cols (coalesced float4)
#pragma unroll
  for (int it = 0; it < 16; ++it) {
    int idx = it * 256 + t;  // 0..4095
    int r = idx >> 5, c4 = idx & 31;
    float4 v = *(const float4*)(src + (size_t)r * ld + nbase + c4 * 4);
    lds[r][c4 * 4 + 0] = v.x;
    lds[r][c4 * 4 + 1] = v.y;
    lds[r][c4 * 4 + 2] = v.z;
    lds[r][c4 * 4 + 3] = v.w;
  }
  __syncthreads();
  // write: thread handles (n = t>>1, k-half = (t&1)*64); column reads stride 129 -> conflict-free
  int n = t >> 1, kh = (t & 1) * 64;
  union { __bf16 b[64]; uint4 u[8]; } H, L;
#pragma unroll
  for (int k = 0; k < 64; ++k) {
    float v = lds[kh + k][n];
    __bf16 hv = (__bf16)v;
    H.b[k] = hv;
    L.b[k] = (__bf16)(v - (float)hv);
  }
  uint4* ph = (uint4*)(wh + (size_t)(nbase + n) * 128 + kh);
  uint4* pl = (uint4*)(wl + (size_t)(nbase + n) * 128 + kh);
#pragma unroll
  for (int i = 0; i < 8; ++i) { ph[i] = H.u[i]; pl[i] = L.u[i]; }
}

__global__ __launch_bounds__(256) void k_prep(
    const float* __restrict__ w2_rad, const float* __restrict__ wo2,
    const float* __restrict__ wo3,
    const int* __restrict__ abs_idx, const float* __restrict__ h,
    const float* __restrict__ wg1,
    __bf16* w2rt_h, __bf16* w2rt_l, __bf16* w2t_h, __bf16* w2t_l,
    __bf16* w3t_h, __bf16* w3t_l,
    float* habs_g, float* vabs, int* widx, int* count) {
  __shared__ float lds[128][129];
  int bid = blockIdx.x;
  int t = threadIdx.x;
  if (bid < 36) {
    transpose_split(w2_rad, 4608, bid * 128, w2rt_h, w2rt_l, lds);
  } else if (bid < 37) {
    transpose_split(wo2, 128, 0, w2t_h, w2t_l, lds);
  } else if (bid < 39) {
    transpose_split(wo3, 256, (bid - 37) * 128, w3t_h, w3t_l, lds);
  } else if (bid < 71) {
    // gabs: 2 batches per block
    float* hs = &lds[0][0];  // [2][128]
    int half = t >> 7, tt = t & 127;
    int b = (bid - 39) * 2 + half;
    int nabs = abs_idx[b];
    hs[half * 128 + tt] = h[(size_t)(b * 128 + nabs) * 128 + tt];
    __syncthreads();
    float g = 0.f;
    for (int c = 0; c < 128; ++c) g = fmaf(hs[half * 128 + c], wg1[c * 128 + tt], g);
    habs_g[b * 128 + tt] = g;
  } else {
    int g = (bid - 71) * 256 + t;
    if (g < FLAT) widx[g] = -1;
    if (g < NB * OD_) vabs[g] = 0.f;
    if (g == 0) *count = 0;
  }
}

// ---------------- scatter: last-write-wins == max edge index ----------------
__global__ void k_scatter(const int* __restrict__ att_dst, int* widx) {
  int i = blockIdx.x * 256 + threadIdx.x;
  if (i < EATT_) atomicMax(&widx[att_dst[i]], i);
}

// ---------------- compact active-node list ----------------
__global__ void k_build(const int* __restrict__ widx, int* active, int* count) {
  int j = blockIdx.x * 256 + threadIdx.x;
  if (j < FLAT && widx[j] >= 0) {
    int p = atomicAdd(count, 1);
    active[p] = j;
  }
}

// ======== k_node4: 4 nodes per block; shared wg1/w1_rad column loads ========
__global__ __launch_bounds__(128) void k_node4(
    const int* __restrict__ count, const int* __restrict__ active,
    const int* __restrict__ widx,
    const float* __restrict__ att_dist, const float* __restrict__ att_vec,
    const int* __restrict__ z, const float* __restrict__ w_zemb,
    const int* __restrict__ abs_idx,
    const float* __restrict__ w1_rad, const float* __restrict__ b1_rad,
    const float* __restrict__ h, const float* __restrict__ habs_g,
    const float* __restrict__ wg1, const float* __restrict__ bg1,
    const float* __restrict__ wg2, const float* __restrict__ bg2,
    const float* __restrict__ h_full,
    __bf16* ah_glob, __bf16* al_glob,
    float* coef_glob, float* meta_f, int* meta_b) {
  int cnt = *count;
  int pbase = blockIdx.x * 4;
  if (pbase >= cnt) return;
  int t = threadIdx.x;  // 128

  __shared__ float win[4][49];
  __shared__ float yv_s[4][3];
  __shared__ float sh_d[4];
  __shared__ float red[4][128];
  __shared__ float hsh[4][128];

  bool ok[4];
  int jj[4], ee[4], bb[4];
  float isab[4];
#pragma unroll
  for (int q = 0; q < 4; ++q) {
    int pos = pbase + q;
    ok[q] = pos < cnt;
    jj[q] = ok[q] ? active[pos] : 0;
    ee[q] = ok[q] ? widx[jj[q]] : 0;
    if (ee[q] < 0) ee[q] = 0;
    bb[q] = jj[q] >> 7;
    isab[q] = ((jj[q] & 127) == abs_idx[bb[q]]) ? 1.f : 0.f;
  }

  if (t < 4) {
    int q = t;
    float d = att_dist[ee[q]];
    sh_d[q] = d;
    float eps = fmaxf(d, 1e-8f);
    const float s3 = 1.7320508075688772f;
    yv_s[q][0] = s3 * att_vec[ee[q] * 3 + 0] / eps;
    yv_s[q][1] = s3 * att_vec[ee[q] * 3 + 1] / eps;
    yv_s[q][2] = s3 * att_vec[ee[q] * 3 + 2] / eps;
  }
#pragma unroll
  for (int q = 0; q < 4; ++q) {
    if (t < 32) win[q][t] = w_zemb[z[jj[q]] * 32 + t];
    if (t == 32) win[q][32] = isab[q];
    if (t >= 33 && t < 49) {
      int k = t - 33;
      float d = att_dist[ee[q]];
      float x = (d - (float)k * (1.f / 3.f)) * 3.f;  // width = 1/3
      win[q][t] = __expf(-0.5f * x * x);
    }
    hsh[q][t] = h[(size_t)jj[q] * 128 + t];
  }
  __syncthreads();

  // hidden a = silu(win @ w1_rad + b1) per node, w1_rad column loaded once
  {
    float s[4];
    float bv = b1_rad[t];
#pragma unroll
    for (int q = 0; q < 4; ++q) s[q] = bv;
    for (int k = 0; k < 49; ++k) {
      float wv = w1_rad[k * 128 + t];
#pragma unroll
      for (int q = 0; q < 4; ++q) s[q] = fmaf(win[q][k], wv, s[q]);
    }
#pragma unroll
    for (int q = 0; q < 4; ++q) {
      if (ok[q]) {
        float av = silu_f(s[q]);
        __bf16 hv = (__bf16)av;
        ah_glob[(size_t)(pbase + q) * 128 + t] = hv;
        al_glob[(size_t)(pbase + q) * 128 + t] = (__bf16)(av - (float)hv);
      }
    }
  }

  // gate MLP hidden (273 -> 128), wg1 column loaded once per c
  {
    float g[4];
#pragma unroll
    for (int q = 0; q < 4; ++q) g[q] = bg1[t] + habs_g[bb[q] * 128 + t];
    for (int c = 0; c < 128; ++c) {
      float wv = wg1[(128 + c) * 128 + t];
#pragma unroll
      for (int q = 0; q < 4; ++q) g[q] = fmaf(hsh[q][c], wv, g[q]);
    }
    for (int k = 0; k < 16; ++k) {
      float wv = wg1[(256 + k) * 128 + t];
#pragma unroll
      for (int q = 0; q < 4; ++q) g[q] = fmaf(win[q][33 + k], wv, g[q]);
    }
    {
      float wv = wg1[272 * 128 + t];
#pragma unroll
      for (int q = 0; q < 4; ++q) g[q] = fmaf(isab[q], wv, g[q]);
    }
    float w2v = wg2[t];
#pragma unroll
    for (int q = 0; q < 4; ++q) red[q][t] = silu_f(g[q]) * w2v;
  }
  __syncthreads();

  // per-node contraction coefficients: [s1(64), p*inv_s3(32), v1(96)]
#pragma unroll
  for (int q = 0; q < 4; ++q) {
    if (!ok[q]) continue;
    int pos = pbase + q;
    const float* hf = h_full + (size_t)jj[q] * 160;
    if (t < 64) coef_glob[pos * 192 + t] = hf[t];
    if (t >= 64 && t < 96) {
      int i = t - 64;
      float pv = hf[64 + i * 3 + 0] * yv_s[q][0] + hf[64 + i * 3 + 1] * yv_s[q][1] +
                 hf[64 + i * 3 + 2] * yv_s[q][2];
      coef_glob[pos * 192 + t] = pv * 0.5773502691896258f;
    }
    if (t < 96) coef_glob[pos * 192 + 96 + t] = hf[64 + t];
  }

  if (t < 4) {
    int q = t;
    if (ok[q]) {
      int pos = pbase + q;
      float tot = 0.f;
      for (int k = 0; k < 128; ++k) tot += red[q][k];
      tot += bg2[0];
      float gate = sigm_f(tot);
      float d = sh_d[q];
      float env = (d < 5.f) ? 0.5f * (__cosf(3.14159265358979323846f * d * 0.2f) + 1.f) : 0.f;
      meta_f[pos * 4 + 0] = yv_s[q][0];
      meta_f[pos * 4 + 1] = yv_s[q][1];
      meta_f[pos * 4 + 2] = yv_s[q][2];
      meta_f[pos * 4 + 3] = gate * env;
      meta_b[pos] = bb[q];
    }
  }
}

// ---------------- split-bf16 MFMA radial GEMM + fused contraction ----------------
__global__ __launch_bounds__(256) void k_mrgemm(
    const int* __restrict__ count,
    const __bf16* Ah, const __bf16* Al,
    const __bf16* __restrict__ Bh, const __bf16* __restrict__ Bl,
    const float* __restrict__ b2, const float* __restrict__ coef_glob,
    float* __restrict__ part) {
  int cc = blockIdx.x;            // 0..35
  int nbase = blockIdx.y * 128;   // 32 y-blocks
  int cnt = *count;
  if (nbase >= cnt) return;
  int t = threadIdx.x;
  int w = t >> 6, l = t & 63;
  int kg = l >> 4, ln = l & 15;
  int cbase = cc * 128;

  __shared__ v8bf Bs[2][2][8][64];   // [buf][plane][nt][lane] 32 KB

  size_t brow0 = (size_t)(cbase + w * 16 + ln) * 128 + kg * 8;
  size_t brow1 = (size_t)(cbase + (w + 4) * 16 + ln) * 128 + kg * 8;
  size_t arow0 = (size_t)(nbase + (2 * w) * 16 + ln) * 128 + kg * 8;
  size_t arow1 = (size_t)(nbase + (2 * w + 1) * 16 + ln) * 128 + kg * 8;

  v8bf rb0 = *(const v8bf*)(Bh + brow0);
  v8bf rb1 = *(const v8bf*)(Bh + brow1);
  v8bf rb2 = *(const v8bf*)(Bl + brow0);
  v8bf rb3 = *(const v8bf*)(Bl + brow1);
  v8bf ah0 = *(const v8bf*)(Ah + arow0);
  v8bf al0 = *(const v8bf*)(Al + arow0);
  v8bf ah1 = *(const v8bf*)(Ah + arow1);
  v8bf al1 = *(const v8bf*)(Al + arow1);
  Bs[0][0][w][l]     = rb0;
  Bs[0][0][w + 4][l] = rb1;
  Bs[0][1][w][l]     = rb2;
  Bs[0][1][w + 4][l] = rb3;
  __syncthreads();

  v4f acc[2][8];
  v4f z4 = {0.f, 0.f, 0.f, 0.f};
#pragma unroll
  for (int i = 0; i < 2; ++i)
#pragma unroll
    for (int j = 0; j < 8; ++j) acc[i][j] = z4;

  for (int kb = 0; kb < 4; ++kb) {
    int cur = kb & 1;
    v8bf nb0, nb1, nb2, nb3, nh0, nl0, nh1, nl1;
    if (kb < 3) {
      int off = (kb + 1) * 32;
      nb0 = *(const v8bf*)(Bh + brow0 + off);
      nb1 = *(const v8bf*)(Bh + brow1 + off);
      nb2 = *(const v8bf*)(Bl + brow0 + off);
      nb3 = *(const v8bf*)(Bl + brow1 + off);
      nh0 = *(const v8bf*)(Ah + arow0 + off);
      nl0 = *(const v8bf*)(Al + arow0 + off);
      nh1 = *(const v8bf*)(Ah + arow1 + off);
      nl1 = *(const v8bf*)(Al + arow1 + off);
    }
#pragma unroll
    for (int nt = 0; nt < 8; ++nt) {
      v8bf bh = Bs[cur][0][nt][l];
      v8bf bl = Bs[cur][1][nt][l];
      acc[0][nt] = __builtin_amdgcn_mfma_f32_16x16x32_bf16(ah0, bh, acc[0][nt], 0, 0, 0);
      acc[0][nt] = __builtin_amdgcn_mfma_f32_16x16x32_bf16(al0, bh, acc[0][nt], 0, 0, 0);
      acc[0][nt] = __builtin_amdgcn_mfma_f32_16x16x32_bf16(ah0, bl, acc[0][nt], 0, 0, 0);
      acc[1][nt] = __builtin_amdgcn_mfma_f32_16x16x32_bf16(ah1, bh, acc[1][nt], 0, 0, 0);
      acc[1][nt] = __builtin_amdgcn_mfma_f32_16x16x32_bf16(al1, bh, acc[1][nt], 0, 0, 0);
      acc[1][nt] = __builtin_amdgcn_mfma_f32_16x16x32_bf16(ah1, bl, acc[1][nt], 0, 0, 0);
    }
    if (kb < 3) {
      int nxt = cur ^ 1;
      Bs[nxt][0][w][l]     = nb0;
      Bs[nxt][0][w + 4][l] = nb1;
      Bs[nxt][1][w][l]     = nb2;
      Bs[nxt][1][w + 4][l] = nb3;
      ah0 = nh0; al0 = nl0; ah1 = nh1; al1 = nl1;
    }
    __syncthreads();
  }

  float b2v[8];
#pragma unroll
  for (int nt = 0; nt < 8; ++nt) b2v[nt] = b2[cbase + nt * 16 + ln];

#pragma unroll
  for (int mi = 0; mi < 2; ++mi) {
    int nodeb = nbase + (2 * w + mi) * 16 + kg * 4;
#pragma unroll
    for (int j = 0; j < 4; ++j) {
      int nd = nodeb + j;
      if (nd >= cnt) continue;
      const float* cf = coef_glob + (size_t)nd * 192;
      if (cc < 24) {
        float s0 = 0.f, s1 = 0.f;
#pragma unroll
        for (int m = 0; m < 4; ++m) {
          float c = cf[cc * 4 + m];
          s0 = fmaf(acc[mi][2 * m][j] + b2v[2 * m], c, s0);
          s1 = fmaf(acc[mi][2 * m + 1][j] + b2v[2 * m + 1], c, s1);
        }
        float* pp = part + (size_t)nd * PARTW + cc * 32 + ln;
        pp[0]  = s0;
        pp[16] = s1;
      } else if (cc < 32) {
        float s = 0.f;
#pragma unroll
        for (int nt = 0; nt < 8; ++nt)
          s = fmaf(acc[mi][nt][j] + b2v[nt], cf[(cc - 24) * 8 + nt], s);
        part[(size_t)nd * PARTW + 768 + (cc - 24) * 16 + ln] = s;
      } else {
        float s0 = 0.f, s1 = 0.f, s2 = 0.f;
#pragma unroll
        for (int nt = 0; nt < 8; ++nt) {
          float x = acc[mi][nt][j] + b2v[nt];
          const float* c3 = cf + 96 + ((cc - 32) * 8 + nt) * 3;
          s0 = fmaf(x, c3[0], s0);
          s1 = fmaf(x, c3[1], s1);
          s2 = fmaf(x, c3[2], s2);
        }
        float* pp = part + (size_t)nd * PARTW + 896 + (cc - 32) * 48 + ln;
        pp[0]  = s0;
        pp[16] = s1;
        pp[32] = s2;
      }
    }
  }
}

// ============ k_post: combine (blocks 0..2047) + scales (blocks 2048..2559) ============
__global__ __launch_bounds__(256) void k_post(
    const int* __restrict__ count, const float* __restrict__ part,
    const float* __restrict__ meta_f, const int* __restrict__ meta_b, float* vabs,
    const float* __restrict__ e_feat,
    const float* __restrict__ we1, const float* __restrict__ be1,
    const float* __restrict__ we2, const float* __restrict__ be2, float* sfull) {
  __shared__ float hid[128];
  int t = threadIdx.x;
  if (blockIdx.x < 2048) {
    int pos = blockIdx.x * 2 + (t >> 7);
    int slot = t & 127;
    if (pos >= *count || slot >= 96) return;
    const float* pp = part + (size_t)pos * PARTW;
    float s = 0.f;
    if (slot < 32) {
#pragma unroll
      for (int c = 0; c < 24; ++c) s += pp[c * 32 + slot];
    } else if (slot < 48) {
#pragma unroll
      for (int c = 0; c < 8; ++c) s += pp[768 + c * 16 + (slot - 32)];
    } else {
#pragma unroll
      for (int c = 0; c < 4; ++c) s += pp[896 + c * 48 + (slot - 48)];
    }
    float sc = meta_f[pos * 4 + 3] * 0.10206207261596577f;  // gate*env / sqrt(96)
    float* vb = vabs + meta_b[pos] * 80;
    if (slot < 32) {
      unsafeAtomicAdd(&vb[slot], s * sc);
    } else if (slot < 48) {
      int o = slot - 32;
      float q = s * sc;
      unsafeAtomicAdd(&vb[32 + o * 3 + 0], q * meta_f[pos * 4 + 0]);
      unsafeAtomicAdd(&vb[32 + o * 3 + 1], q * meta_f[pos * 4 + 1]);
      unsafeAtomicAdd(&vb[32 + o * 3 + 2], q * meta_f[pos * 4 + 2]);
    } else {
      int s2 = slot - 48;          // comp*16 + o
      int comp = s2 >> 4, o = s2 & 15;
      unsafeAtomicAdd(&vb[32 + o * 3 + comp], s * sc);
    }
  } else {
    int row = blockIdx.x - 2048;   // 512
    if (t < 128) {
      const float* ef = e_feat + row * 16;
      float s = be1[t];
      for (int k = 0; k < 16; ++k) s = fmaf(ef[k], we1[k * 128 + t], s);
      hid[t] = silu_f(s);
    }
    __syncthreads();
    if (t < 48) {
      float o = be2[t];
      for (int k = 0; k < 128; ++k) o = fmaf(hid[k], we2[k * 48 + t], o);
      if (t < 32) sfull[row * 80 + t] = o;
      else {
        int oo = t - 32;
        sfull[row * 80 + 32 + oo * 3 + 0] = o;
        sfull[row * 80 + 32 + oo * 3 + 1] = o;
        sfull[row * 80 + 32 + oo * 3 + 2] = o;
      }
    }
  }
}

// ---------------- head G1: build inv + (32768x48)@wo1 + silu -> xh/xl (bf16 hi/lo) ----------------
__global__ __launch_bounds__(256) void k_hg1(const float* __restrict__ vabs,
                                             const float* __restrict__ sfull,
                                             const float* __restrict__ wo1,
                                             const float* __restrict__ bo1,
                                             __bf16* __restrict__ xh,
                                             __bf16* __restrict__ xl) {
  int rbase = blockIdx.x * 64;   // 512 blocks
  int b = rbase >> 9;
  int e0 = rbase & 511;
  int t = threadIdx.x;
  int tx = t & 15, ty = t >> 4;
  int n0 = ty * 4;

  __shared__ float w_s[48 * 128];   // [k][col], 24 KB
  __shared__ float invt[48][64];    // [k][row], 12 KB
  __shared__ float va[80];

  if (t < 80) va[t] = vabs[b * 80 + t];
  {
    const float4* wg = (const float4*)wo1;
    float4* ws4 = (float4*)w_s;
#pragma unroll
    for (int it = 0; it < 6; ++it) ws4[t + it * 256] = wg[t + it * 256];
  }
  __syncthreads();

  for (int idx = t; idx < 48 * 64; idx += 256) {
    int cd = idx >> 6, r = idx & 63;
    const float* sf = sfull + (size_t)(e0 + r) * 80;
    float v;
    if (cd < 32) v = va[cd] * sf[cd];
    else {
      int base = 32 + (cd - 32) * 3;
      float m0 = va[base + 0] * sf[base + 0];
      float m1 = va[base + 1] * sf[base + 1];
      float m2 = va[base + 2] * sf[base + 2];
      v = sqrtf(m0 * m0 + m1 * m1 + m2 * m2 + 1e-12f);
    }
    invt[cd][r] = v;
  }
  __syncthreads();

  float acc[4][8];
#pragma unroll
  for (int i = 0; i < 4; ++i)
#pragma unroll
    for (int j = 0; j < 8; ++j) acc[i][j] = 0.f;

  for (int k = 0; k < 48; ++k) {
    float4 av  = *(const float4*)&invt[k][n0];
    float4 w0  = *(const float4*)&w_s[k * 128 + tx * 4];
    float4 w1v = *(const float4*)&w_s[k * 128 + 64 + tx * 4];
#pragma unroll
    for (int i = 0; i < 4; ++i) {
      float a = (i == 0) ? av.x : (i == 1) ? av.y : (i == 2) ? av.z : av.w;
      acc[i][0] = fmaf(a, w0.x,  acc[i][0]);
      acc[i][1] = fmaf(a, w0.y,  acc[i][1]);
      acc[i][2] = fmaf(a, w0.z,  acc[i][2]);
      acc[i][3] = fmaf(a, w0.w,  acc[i][3]);
      acc[i][4] = fmaf(a, w1v.x, acc[i][4]);
      acc[i][5] = fmaf(a, w1v.y, acc[i][5]);
      acc[i][6] = fmaf(a, w1v.z, acc[i][6]);
      acc[i][7] = fmaf(a, w1v.w, acc[i][7]);
    }
  }

  float4 bq0 = *(const float4*)(bo1 + tx * 4);
  float4 bq1 = *(const float4*)(bo1 + 64 + tx * 4);
#pragma unroll
  for (int i = 0; i < 4; ++i) {
    size_t row = (size_t)(rbase + n0 + i);
    float q0[4] = {silu_f(acc[i][0] + bq0.x), silu_f(acc[i][1] + bq0.y),
                   silu_f(acc[i][2] + bq0.z), silu_f(acc[i][3] + bq0.w)};
    float q1[4] = {silu_f(acc[i][4] + bq1.x), silu_f(acc[i][5] + bq1.y),
                   silu_f(acc[i][6] + bq1.z), silu_f(acc[i][7] + bq1.w)};
    union { __bf16 bb[4]; uint2 u; } H, L;
#pragma unroll
    for (int e = 0; e < 4; ++e) {
      __bf16 hv = (__bf16)q0[e];
      H.bb[e] = hv;
      L.bb[e] = (__bf16)(q0[e] - (float)hv);
    }
    *(uint2*)(xh + row * 128 + tx * 4) = H.u;
    *(uint2*)(xl + row * 128 + tx * 4) = L.u;
#pragma unroll
    for (int e = 0; e < 4; ++e) {
      __bf16 hv = (__bf16)q1[e];
      H.bb[e] = hv;
      L.bb[e] = (__bf16)(q1[e] - (float)hv);
    }
    *(uint2*)(xh + row * 128 + 64 + tx * 4) = H.u;
    *(uint2*)(xl + row * 128 + 64 + tx * 4) = L.u;
  }
}

// ---------------- split-bf16 MFMA GEMM for head layers 2/3 ----------------
template<int MODE>
__global__ __launch_bounds__(256) void k_mgemm(
    const __bf16* Ah, const __bf16* Al,
    const __bf16* __restrict__ Bh, const __bf16* __restrict__ Bl,
    const float* __restrict__ bias,
    __bf16* Oh, __bf16* Ol, float* __restrict__ Of) {
  int rbase = blockIdx.y * 64;
  int cbase = blockIdx.x * 128;
  int t = threadIdx.x;
  int w = t >> 6;            // wave = M-tile
  int l = t & 63;
  int kg = l >> 4, ln = l & 15;

  __shared__ v8bf As[2][2][4][64];   // [buf][plane][mt][lane]  16 KB
  __shared__ v8bf Bs[2][2][8][64];   // [buf][plane][nt][lane]  32 KB

  size_t arow  = (size_t)(rbase + w * 16 + ln) * 128 + kg * 8;
  int nt0 = w, nt1 = w + 4;
  size_t brow0 = (size_t)(cbase + nt0 * 16 + ln) * 128 + kg * 8;
  size_t brow1 = (size_t)(cbase + nt1 * 16 + ln) * 128 + kg * 8;

  v8bf ra0, ra1, rb0, rb1, rb2, rb3;
  ra0 = *(const v8bf*)(Ah + arow);
  ra1 = *(const v8bf*)(Al + arow);
  rb0 = *(const v8bf*)(Bh + brow0);
  rb1 = *(const v8bf*)(Bh + brow1);
  rb2 = *(const v8bf*)(Bl + brow0);
  rb3 = *(const v8bf*)(Bl + brow1);
  As[0][0][w][l]   = ra0;
  As[0][1][w][l]   = ra1;
  Bs[0][0][nt0][l] = rb0;
  Bs[0][0][nt1][l] = rb1;
  Bs[0][1][nt0][l] = rb2;
  Bs[0][1][nt1][l] = rb3;
  __syncthreads();

  v4f acc[8];
  v4f z4 = {0.f, 0.f, 0.f, 0.f};
#pragma unroll
  for (int i = 0; i < 8; ++i) acc[i] = z4;

  for (int kb = 0; kb < 4; ++kb) {
    int cur = kb & 1;
    if (kb < 3) {
      int off = (kb + 1) * 32;
      ra0 = *(const v8bf*)(Ah + arow + off);
      ra1 = *(const v8bf*)(Al + arow + off);
      rb0 = *(const v8bf*)(Bh + brow0 + off);
      rb1 = *(const v8bf*)(Bh + brow1 + off);
      rb2 = *(const v8bf*)(Bl + brow0 + off);
      rb3 = *(const v8bf*)(Bl + brow1 + off);
    }
    v8bf ah  = As[cur][0][w][l];
    v8bf alo = As[cur][1][w][l];
#pragma unroll
    for (int nt = 0; nt < 8; ++nt) {
      v8bf bh = Bs[cur][0][nt][l];
      v8bf bl = Bs[cur][1][nt][l];
      acc[nt] = __builtin_amdgcn_mfma_f32_16x16x32_bf16(ah,  bh, acc[nt], 0, 0, 0);
      acc[nt] = __builtin_amdgcn_mfma_f32_16x16x32_bf16(alo, bh, acc[nt], 0, 0, 0);
      acc[nt] = __builtin_amdgcn_mfma_f32_16x16x32_bf16(ah,  bl, acc[nt], 0, 0, 0);
    }
    if (kb < 3) {
      int nxt = cur ^ 1;
      As[nxt][0][w][l]   = ra0;
      As[nxt][1][w][l]   = ra1;
      Bs[nxt][0][nt0][l] = rb0;
      Bs[nxt][0][nt1][l] = rb1;
      Bs[nxt][1][nt0][l] = rb2;
      Bs[nxt][1][nt1][l] = rb3;
    }
    __syncthreads();
  }

  int r0 = rbase + w * 16 + kg * 4;
#pragma unroll
  for (int nt = 0; nt < 8; ++nt) {
    float bv = bias[cbase + nt * 16 + ln];
#pragma unroll
    for (int j = 0; j < 4; ++j) {
      float x = acc[nt][j] + bv;
      if (MODE == 0) {
        x = silu_f(x);
        __bf16 hv = (__bf16)x;
        size_t o = (size_t)(r0 + j) * 128 + nt * 16 + ln;
        Oh[o] = hv;
        Ol[o] = (__bf16)(x - (float)hv);
      } else {
        Of[(size_t)(r0 + j) * 256 + cbase + nt * 16 + ln] = x;
      }
    }
  }
}

extern "C" void kernel_launch(void* const* d_in, const int* in_sizes, int n_in,
                              void* d_out, int out_size, void* d_ws, size_t ws_size,
                              hipStream_t stream) {
  const float* h        = (const float*)d_in[0];
  const float* h_full   = (const float*)d_in[1];
  const int*   z        = (const int*)d_in[2];
  const float* e_feat   = (const float*)d_in[4];
  const int*   abs_idx  = (const int*)d_in[5];
  const int*   att_dst  = (const int*)d_in[6];
  const float* att_dist = (const float*)d_in[7];
  const float* att_vec  = (const float*)d_in[8];
  const float* w_zemb   = (const float*)d_in[9];
  const float* w1_rad   = (const float*)d_in[10];
  const float* b1_rad   = (const float*)d_in[11];
  const float* w2_rad   = (const float*)d_in[12];
  const float* b2_rad   = (const float*)d_in[13];
  const float* wg1      = (const float*)d_in[14];
  const float* bg1      = (const float*)d_in[15];
  const float* wg2      = (const float*)d_in[16];
  const float* bg2      = (const float*)d_in[17];
  const float* we1      = (const float*)d_in[18];
  const float* be1      = (const float*)d_in[19];
  const float* we2      = (const float*)d_in[20];
  const float* be2      = (const float*)d_in[21];
  const float* wo1      = (const float*)d_in[22];
  const float* bo1      = (const float*)d_in[23];
  const float* wo2      = (const float*)d_in[24];
  const float* bo2      = (const float*)d_in[25];
  const float* wo3      = (const float*)d_in[26];
  const float* bo3      = (const float*)d_in[27];
  float* out = (float*)d_out;

  // workspace: persistent small buffers, then big region where
  // phase-1 (ah/al/coef/w2rt/part, ~25 MB) and phase-2 (xh+xl, 16 MB) alias.
  float* meta_f  = (float*)d_ws;                 // MAXACT*4
  float* vabs    = meta_f + MAXACT * 4;          // 64*80
  float* sfull   = vabs + NB * OD_;              // 512*80
  float* habs_g  = sfull + NE_ * OD_;            // 64*128
  __bf16* w2t_h  = (__bf16*)(habs_g + NB * 128); // 128*128 bf16
  __bf16* w2t_l  = w2t_h + 128 * 128;
  __bf16* w3t_h  = w2t_l + 128 * 128;            // 256*128 bf16
  __bf16* w3t_l  = w3t_h + 256 * 128;
  int* widx   = (int*)(w3t_l + 256 * 128);       // 8192
  int* active = widx + FLAT;                     // 4096
  int* meta_b = active + MAXACT;                 // 4096
  int* count  = meta_b + MAXACT;                 // 1 (+pad to 16B)
  float* big  = (float*)(count + 15);            // aligned big region
  // phase 1:
  __bf16* ah_glob  = (__bf16*)big;               // MAXACT*128
  __bf16* al_glob  = ah_glob + MAXACT * 128;     // MAXACT*128
  float* coef_glob = (float*)(al_glob + MAXACT * 128);  // MAXACT*192
  __bf16* w2rt_h   = (__bf16*)(coef_glob + MAXACT * 192); // 4608*128
  __bf16* w2rt_l   = w2rt_h + 4608 * 128;
  float* part      = (float*)(w2rt_l + 4608 * 128);     // MAXACT*1088 (17.8 MB)
  // phase 2 (aliases phase 1, all phase-1 consumers done before k_hg1):
  __bf16* xh       = (__bf16*)big;               // 32768*128
  __bf16* xl       = xh + (size_t)32768 * 128;   // 32768*128

  k_prep<<<103, 256, 0, stream>>>(w2_rad, wo2, wo3, abs_idx, h, wg1,
                                  w2rt_h, w2rt_l, w2t_h, w2t_l, w3t_h, w3t_l,
                                  habs_g, vabs, widx, count);
  k_scatter<<<16, 256, 0, stream>>>(att_dst, widx);
  k_build<<<32, 256, 0, stream>>>(widx, active, count);
  k_node4<<<1024, 128, 0, stream>>>(count, active, widx, att_dist, att_vec, z, w_zemb,
                                    abs_idx, w1_rad, b1_rad, h, habs_g, wg1, bg1, wg2, bg2,
                                    h_full, ah_glob, al_glob, coef_glob, meta_f, meta_b);
  k_mrgemm<<<dim3(36, 32), 256, 0, stream>>>(count, ah_glob, al_glob, w2rt_h, w2rt_l,
                                             b2_rad, coef_glob, part);
  k_post<<<2560, 256, 0, stream>>>(count, part, meta_f, meta_b, vabs,
                                   e_feat, we1, be1, we2, be2, sfull);
  k_hg1<<<512, 256, 0, stream>>>(vabs, sfull, wo1, bo1, xh, xl);
  k_mgemm<0><<<dim3(1, 512), 256, 0, stream>>>(xh, xl, w2t_h, w2t_l, bo2,
                                               xh, xl, nullptr);
  k_mgemm<1><<<dim3(2, 512), 256, 0, stream>>>(xh, xl, w3t_h, w3t_l, bo3,
                                               nullptr, nullptr, out);
}